// Round 1
// baseline (535.426 us; speedup 1.0000x reference)
//
#include <hip/hip_runtime.h>
#include <math.h>

typedef __bf16 bf16_t;
typedef __attribute__((ext_vector_type(8))) __bf16 bf16x8;
typedef __attribute__((ext_vector_type(4))) __bf16 bf16x4;
typedef __attribute__((ext_vector_type(4))) float f32x4;

#define T_LEN 4096
#define C_DIM 1024
#define NH 16
#define HD 64

__device__ __forceinline__ void gload_lds16(const void* g, void* l) {
    __builtin_amdgcn_global_load_lds(
        (__attribute__((address_space(1))) void*)(g),
        (__attribute__((address_space(3))) void*)(l), 16, 0, 0);
}

__device__ __forceinline__ f32x4 mfma16(bf16x8 a, bf16x8 b, f32x4 c) {
    return __builtin_amdgcn_mfma_f32_16x16x32_bf16(a, b, c, 0, 0, 0);
}

__device__ __forceinline__ float gelu_exact(float v) {
    return 0.5f * v * (1.0f + erff(v * 0.7071067811865476f));
}

// ---------------- weight transpose+convert: in fp32 [R][C] -> out bf16 [C][R]
__global__ __launch_bounds__(256) void transpose_w(
    const float* __restrict__ in, bf16_t* __restrict__ out, int R, int C)
{
    __shared__ float tile[32][33];
    const int tx = threadIdx.x, ty = threadIdx.y;
    const int c0 = blockIdx.x * 32, r0 = blockIdx.y * 32;
#pragma unroll
    for (int j = 0; j < 4; ++j)
        tile[ty + j * 8][tx] = in[(size_t)(r0 + ty + j * 8) * C + c0 + tx];
    __syncthreads();
#pragma unroll
    for (int j = 0; j < 4; ++j)
        out[(size_t)(c0 + ty + j * 8) * R + r0 + tx] = (bf16_t)tile[tx][ty + j * 8];
}

// ---------------- per-head V transpose: qkv bf16 [T][3C] -> vt [H][64][T]
__global__ __launch_bounds__(256) void vtrans(
    const bf16_t* __restrict__ qkv, bf16_t* __restrict__ vt)
{
    __shared__ bf16_t tile[32][33];
    const int tx = threadIdx.x, ty = threadIdx.y;
    const int h = blockIdx.z;
    const int t0 = blockIdx.x * 32, d0 = blockIdx.y * 32;
#pragma unroll
    for (int j = 0; j < 4; ++j)
        tile[ty + j * 8][tx] =
            qkv[(size_t)(t0 + ty + j * 8) * 3072 + 2048 + h * 64 + d0 + tx];
    __syncthreads();
#pragma unroll
    for (int j = 0; j < 4; ++j)
        vt[(size_t)h * (64 * 4096) + (size_t)(d0 + ty + j * 8) * 4096 + t0 + tx] =
            tile[tx][ty + j * 8];
}

// ---------------- LayerNorm fp32 -> bf16
__global__ __launch_bounds__(256) void ln_bf16(
    const float* __restrict__ x, const float* __restrict__ gam,
    const float* __restrict__ bet, bf16_t* __restrict__ out)
{
    const int row = blockIdx.x, t = threadIdx.x;
    const float4 v = *(const float4*)(x + (size_t)row * 1024 + t * 4);
    float s1 = v.x + v.y + v.z + v.w;
    float s2 = v.x * v.x + v.y * v.y + v.z * v.z + v.w * v.w;
#pragma unroll
    for (int m = 1; m < 64; m <<= 1) {
        s1 += __shfl_xor(s1, m);
        s2 += __shfl_xor(s2, m);
    }
    __shared__ float red[8];
    if ((t & 63) == 0) { red[(t >> 6) * 2] = s1; red[(t >> 6) * 2 + 1] = s2; }
    __syncthreads();
    s1 = red[0] + red[2] + red[4] + red[6];
    s2 = red[1] + red[3] + red[5] + red[7];
    const float mu = s1 * (1.0f / 1024.0f);
    const float inv = rsqrtf(s2 * (1.0f / 1024.0f) - mu * mu + 1e-5f);
    const float4 gg = *(const float4*)(gam + t * 4);
    const float4 bb = *(const float4*)(bet + t * 4);
    bf16x4 o;
    o[0] = (bf16_t)((v.x - mu) * inv * gg.x + bb.x);
    o[1] = (bf16_t)((v.y - mu) * inv * gg.y + bb.y);
    o[2] = (bf16_t)((v.z - mu) * inv * gg.z + bb.z);
    o[3] = (bf16_t)((v.w - mu) * inv * gg.w + bb.w);
    *(bf16x4*)(out + (size_t)row * 1024 + t * 4) = o;
}

// ---------------- GEMM: C[M][N] = A[M][K](bf16) * Bt[N][K](bf16) + bias
// EPI: 0 = bf16 out, 1 = gelu -> bf16 out, 2 = +res(fp32) -> fp32 out
template <int EPI>
__global__ __launch_bounds__(256) void gemm_bt(
    const bf16_t* __restrict__ A, const bf16_t* __restrict__ Bt,
    const float* __restrict__ bias, const float* __restrict__ res,
    bf16_t* __restrict__ outb, float* __restrict__ outf,
    int M, int N, int K)
{
    __shared__ alignas(1024) bf16_t Alds[128 * 32];
    __shared__ alignas(1024) bf16_t Blds[128 * 32];
    const int t = threadIdx.x;
    const int lane = t & 63, w = t >> 6;
    const int wr = w >> 1, wc = w & 1;
    const int m0 = blockIdx.y * 128, n0 = blockIdx.x * 128;
    const int g = lane >> 4, ci = lane & 15;

    f32x4 acc[4][4];
#pragma unroll
    for (int i = 0; i < 4; ++i)
#pragma unroll
        for (int j = 0; j < 4; ++j)
#pragma unroll
            for (int k = 0; k < 4; ++k) acc[i][j][k] = 0.0f;

    const int r0 = t >> 2;             // staging row (issue 0), 4 chunks/row
    const int cc = (t & 3) * 8;        // staging col (elements)
    char* aB = (char*)Alds + w * 1024;
    char* bB = (char*)Blds + w * 1024;
    const int nkt = K >> 5;
    for (int kt = 0; kt < nkt; ++kt) {
        const int kk = kt * 32;
        gload_lds16(A + (size_t)(m0 + r0) * K + kk + cc, aB);
        gload_lds16(A + (size_t)(m0 + r0 + 64) * K + kk + cc, aB + 4096);
        gload_lds16(Bt + (size_t)(n0 + r0) * K + kk + cc, bB);
        gload_lds16(Bt + (size_t)(n0 + r0 + 64) * K + kk + cc, bB + 4096);
        __syncthreads();
        const bf16_t* ap = Alds + (wr * 64 + ci) * 32 + g * 8;
        const bf16_t* bp = Blds + (wc * 64 + ci) * 32 + g * 8;
        bf16x8 af[4], bf[4];
#pragma unroll
        for (int mt = 0; mt < 4; ++mt) af[mt] = *(const bf16x8*)(ap + mt * 16 * 32);
#pragma unroll
        for (int nt = 0; nt < 4; ++nt) bf[nt] = *(const bf16x8*)(bp + nt * 16 * 32);
#pragma unroll
        for (int mt = 0; mt < 4; ++mt)
#pragma unroll
            for (int nt = 0; nt < 4; ++nt)
                acc[mt][nt] = mfma16(af[mt], bf[nt], acc[mt][nt]);
        __syncthreads();
    }

#pragma unroll
    for (int nt = 0; nt < 4; ++nt) {
        const int col = n0 + wc * 64 + nt * 16 + ci;
        const float bv = bias[col];
#pragma unroll
        for (int mt = 0; mt < 4; ++mt) {
            const int row = m0 + wr * 64 + mt * 16 + g * 4;
#pragma unroll
            for (int r = 0; r < 4; ++r) {
                float v = acc[mt][nt][r] + bv;
                if constexpr (EPI == 1) v = gelu_exact(v);
                if constexpr (EPI == 2) {
                    outf[(size_t)(row + r) * N + col] =
                        v + res[(size_t)(row + r) * N + col];
                } else {
                    outb[(size_t)(row + r) * N + col] = (bf16_t)v;
                }
            }
        }
    }
}

// ---------------- causal flash attention
// qkv bf16 [T][3072] (Q at h*64, K at 1024+h*64, V at 2048+h*64)
// vt  bf16 [H][64][T]  (V transposed per head)
// out bf16 [T][1024]   ([t][h*64+d])
__global__ __launch_bounds__(256) void attn_fwd(
    const bf16_t* __restrict__ qkv, const bf16_t* __restrict__ vt,
    bf16_t* __restrict__ out)
{
    __shared__ alignas(1024) bf16_t Klds[64 * 64];
    __shared__ alignas(1024) bf16_t Vlds[64 * 64];   // [d][kpos]
    __shared__ alignas(1024) bf16_t Plds[4][16 * 72];
    const int t = threadIdx.x, lane = t & 63, w = t >> 6;
    const int g = lane >> 4, ci = lane & 15;
    const int h = blockIdx.y, qt = blockIdx.x, q0 = qt * 64;

    const size_t qrow = (size_t)q0 + w * 16 + ci;
    const bf16x8 qf0 = *(const bf16x8*)(qkv + qrow * 3072 + h * 64 + g * 8);
    const bf16x8 qf1 = *(const bf16x8*)(qkv + qrow * 3072 + h * 64 + 32 + g * 8);

    f32x4 oacc[4];
#pragma unroll
    for (int dt = 0; dt < 4; ++dt)
#pragma unroll
        for (int r = 0; r < 4; ++r) oacc[dt][r] = 0.0f;
    float m_i[4] = {-1e30f, -1e30f, -1e30f, -1e30f};
    float l_i[4] = {0.0f, 0.0f, 0.0f, 0.0f};

    const int sr = t >> 3;            // staging row, 8 chunks/row
    const int sc = (t & 7) * 8;       // staging col (elements)
    char* kB = (char*)Klds + w * 1024;
    char* vB = (char*)Vlds + w * 1024;

    for (int kt = 0; kt <= qt; ++kt) {
        const bf16_t* kg = qkv + (size_t)(kt * 64 + sr) * 3072 + 1024 + h * 64 + sc;
        gload_lds16(kg, kB);
        gload_lds16(kg + (size_t)32 * 3072, kB + 4096);
        const bf16_t* vg = vt + (size_t)h * (64 * 4096) + (size_t)sr * 4096 + kt * 64 + sc;
        gload_lds16(vg, vB);
        gload_lds16(vg + (size_t)32 * 4096, vB + 4096);
        __syncthreads();

        // S = Q K^T (per wave: 16 q-rows x 64 kpos)
        f32x4 s[4];
        const bf16_t* kp = Klds + ci * 64 + g * 8;
#pragma unroll
        for (int nt = 0; nt < 4; ++nt) {
            f32x4 z;
#pragma unroll
            for (int k = 0; k < 4; ++k) z[k] = 0.0f;
            z = mfma16(qf0, *(const bf16x8*)(kp + nt * 1024), z);
            z = mfma16(qf1, *(const bf16x8*)(kp + nt * 1024 + 32), z);
            s[nt] = z;
        }

        const bool diag = (kt == qt);
        float pm[4] = {-1e30f, -1e30f, -1e30f, -1e30f};
#pragma unroll
        for (int nt = 0; nt < 4; ++nt)
#pragma unroll
            for (int r = 0; r < 4; ++r) {
                float sv = s[nt][r] * 0.125f;
                if (diag && (nt * 16 + ci > w * 16 + g * 4 + r)) sv = -1e30f;
                s[nt][r] = sv;
                pm[r] = fmaxf(pm[r], sv);
            }
#pragma unroll
        for (int r = 0; r < 4; ++r)
#pragma unroll
            for (int m = 1; m < 16; m <<= 1)
                pm[r] = fmaxf(pm[r], __shfl_xor(pm[r], m));

        float newm[4], sc_[4], rs[4], ps[4][4];
#pragma unroll
        for (int r = 0; r < 4; ++r) { newm[r] = fmaxf(m_i[r], pm[r]); rs[r] = 0.0f; }
#pragma unroll
        for (int nt = 0; nt < 4; ++nt)
#pragma unroll
            for (int r = 0; r < 4; ++r) {
                float p = exp2f((s[nt][r] - newm[r]) * 1.4426950408889634f);
                ps[nt][r] = p;
                rs[r] += p;
            }
#pragma unroll
        for (int r = 0; r < 4; ++r) {
#pragma unroll
            for (int m = 1; m < 16; m <<= 1) rs[r] += __shfl_xor(rs[r], m);
            sc_[r] = exp2f((m_i[r] - newm[r]) * 1.4426950408889634f);
            l_i[r] = l_i[r] * sc_[r] + rs[r];
            m_i[r] = newm[r];
        }
#pragma unroll
        for (int dt = 0; dt < 4; ++dt)
#pragma unroll
            for (int r = 0; r < 4; ++r) oacc[dt][r] *= sc_[r];

        // P -> LDS (per-wave buffer), reshape into A-fragments
        bf16_t* pl = &Plds[w][0];
#pragma unroll
        for (int nt = 0; nt < 4; ++nt)
#pragma unroll
            for (int r = 0; r < 4; ++r)
                pl[(g * 4 + r) * 72 + nt * 16 + ci] = (bf16_t)ps[nt][r];
        asm volatile("s_waitcnt lgkmcnt(0)" ::: "memory");

        const bf16_t* pp = pl + ci * 72;
        const bf16x8 pf0 = *(const bf16x8*)(pp + g * 8);
        const bf16x8 pf1 = *(const bf16x8*)(pp + 32 + g * 8);
        const bf16_t* vp = Vlds + ci * 64 + g * 8;
#pragma unroll
        for (int dt = 0; dt < 4; ++dt) {
            oacc[dt] = mfma16(pf0, *(const bf16x8*)(vp + dt * 1024), oacc[dt]);
            oacc[dt] = mfma16(pf1, *(const bf16x8*)(vp + dt * 1024 + 32), oacc[dt]);
        }
        __syncthreads();
    }

#pragma unroll
    for (int r = 0; r < 4; ++r) {
        const float inv = 1.0f / l_i[r];
        const size_t row = (size_t)q0 + w * 16 + g * 4 + r;
#pragma unroll
        for (int dt = 0; dt < 4; ++dt)
            out[row * 1024 + h * 64 + dt * 16 + ci] = (bf16_t)(oacc[dt][r] * inv);
    }
}

extern "C" void kernel_launch(void* const* d_in, const int* in_sizes, int n_in,
                              void* d_out, int out_size, void* d_ws, size_t ws_size,
                              hipStream_t stream)
{
    const float* x    = (const float*)d_in[0];
    const float* ln1g = (const float*)d_in[1];
    const float* ln1b = (const float*)d_in[2];
    const float* Wqkv = (const float*)d_in[3];
    const float* bqkv = (const float*)d_in[4];
    const float* Wo   = (const float*)d_in[5];
    const float* bo   = (const float*)d_in[6];
    const float* ln2g = (const float*)d_in[7];
    const float* ln2b = (const float*)d_in[8];
    const float* W1   = (const float*)d_in[9];
    const float* b1   = (const float*)d_in[10];
    const float* W2   = (const float*)d_in[11];
    const float* b2   = (const float*)d_in[12];
    float* outp = (float*)d_out;

    char* p = (char*)d_ws;
    bf16_t* WqkvT = (bf16_t*)p; p += (size_t)3072 * 1024 * 2;
    bf16_t* WoT   = (bf16_t*)p; p += (size_t)1024 * 1024 * 2;
    bf16_t* W1T   = (bf16_t*)p; p += (size_t)4096 * 1024 * 2;
    bf16_t* W2T   = (bf16_t*)p; p += (size_t)1024 * 4096 * 2;
    bf16_t* xn    = (bf16_t*)p; p += (size_t)4096 * 1024 * 2;
    bf16_t* qkv   = (bf16_t*)p; p += (size_t)4096 * 3072 * 2;
    bf16_t* vtb   = (bf16_t*)p; p += (size_t)16 * 64 * 4096 * 2;
    bf16_t* attnb = (bf16_t*)p; p += (size_t)4096 * 1024 * 2;
    float*  x2    = (float*)p;  p += (size_t)4096 * 1024 * 4;
    bf16_t* hb    = (bf16_t*)p; p += (size_t)4096 * 1024 * 2;
    bf16_t* g1    = (bf16_t*)p; p += (size_t)4096 * 4096 * 2;

    const dim3 tb(32, 8);
    transpose_w<<<dim3(96, 32),  tb, 0, stream>>>(Wqkv, WqkvT, 1024, 3072);
    transpose_w<<<dim3(32, 32),  tb, 0, stream>>>(Wo,   WoT,   1024, 1024);
    transpose_w<<<dim3(128, 32), tb, 0, stream>>>(W1,   W1T,   1024, 4096);
    transpose_w<<<dim3(32, 128), tb, 0, stream>>>(W2,   W2T,   4096, 1024);

    ln_bf16<<<4096, 256, 0, stream>>>(x, ln1g, ln1b, xn);
    gemm_bt<0><<<dim3(24, 32), 256, 0, stream>>>(xn, WqkvT, bqkv, nullptr,
                                                 qkv, nullptr, 4096, 3072, 1024);
    vtrans<<<dim3(128, 2, 16), tb, 0, stream>>>(qkv, vtb);
    attn_fwd<<<dim3(64, 16), 256, 0, stream>>>(qkv, vtb, attnb);
    gemm_bt<2><<<dim3(8, 32), 256, 0, stream>>>(attnb, WoT, bo, x,
                                                nullptr, x2, 4096, 1024, 1024);
    ln_bf16<<<4096, 256, 0, stream>>>(x2, ln2g, ln2b, hb);
    gemm_bt<1><<<dim3(32, 32), 256, 0, stream>>>(hb, W1T, b1, nullptr,
                                                 g1, nullptr, 4096, 4096, 1024);
    gemm_bt<2><<<dim3(8, 32), 256, 0, stream>>>(g1, W2T, b2, x2,
                                                nullptr, outp, 4096, 1024, 4096);
}

// Round 2
// 389.825 us; speedup vs baseline: 1.3735x; 1.3735x over previous
//
#include <hip/hip_runtime.h>
#include <math.h>

typedef __bf16 bf16_t;
typedef __attribute__((ext_vector_type(8))) __bf16 bf16x8;
typedef __attribute__((ext_vector_type(4))) __bf16 bf16x4;
typedef __attribute__((ext_vector_type(4))) float f32x4;

#define T_LEN 4096
#define C_DIM 1024
#define NH 16
#define HD 64

__device__ __forceinline__ void gload_lds16(const void* g, void* l) {
    __builtin_amdgcn_global_load_lds(
        (__attribute__((address_space(1))) void*)(g),
        (__attribute__((address_space(3))) void*)(l), 16, 0, 0);
}

__device__ __forceinline__ f32x4 mfma16(bf16x8 a, bf16x8 b, f32x4 c) {
    return __builtin_amdgcn_mfma_f32_16x16x32_bf16(a, b, c, 0, 0, 0);
}

__device__ __forceinline__ float gelu_exact(float v) {
    return 0.5f * v * (1.0f + erff(v * 0.7071067811865476f));
}

// ---------------- weight transpose+convert: in fp32 [R][C] -> out bf16 [C][R]
__global__ __launch_bounds__(256) void transpose_w(
    const float* __restrict__ in, bf16_t* __restrict__ out, int R, int C)
{
    __shared__ float tile[32][33];
    const int tx = threadIdx.x, ty = threadIdx.y;
    const int c0 = blockIdx.x * 32, r0 = blockIdx.y * 32;
#pragma unroll
    for (int j = 0; j < 4; ++j)
        tile[ty + j * 8][tx] = in[(size_t)(r0 + ty + j * 8) * C + c0 + tx];
    __syncthreads();
#pragma unroll
    for (int j = 0; j < 4; ++j)
        out[(size_t)(c0 + ty + j * 8) * R + r0 + tx] = (bf16_t)tile[tx][ty + j * 8];
}

// ---------------- per-head V transpose: qkv bf16 [T][3C] -> vt [H][64][T]
__global__ __launch_bounds__(256) void vtrans(
    const bf16_t* __restrict__ qkv, bf16_t* __restrict__ vt)
{
    __shared__ bf16_t tile[32][33];
    const int tx = threadIdx.x, ty = threadIdx.y;
    const int h = blockIdx.z;
    const int t0 = blockIdx.x * 32, d0 = blockIdx.y * 32;
#pragma unroll
    for (int j = 0; j < 4; ++j)
        tile[ty + j * 8][tx] =
            qkv[(size_t)(t0 + ty + j * 8) * 3072 + 2048 + h * 64 + d0 + tx];
    __syncthreads();
#pragma unroll
    for (int j = 0; j < 4; ++j)
        vt[(size_t)h * (64 * 4096) + (size_t)(d0 + ty + j * 8) * 4096 + t0 + tx] =
            tile[tx][ty + j * 8];
}

// ---------------- LayerNorm fp32 -> bf16
__global__ __launch_bounds__(256) void ln_bf16(
    const float* __restrict__ x, const float* __restrict__ gam,
    const float* __restrict__ bet, bf16_t* __restrict__ out)
{
    const int row = blockIdx.x, t = threadIdx.x;
    const float4 v = *(const float4*)(x + (size_t)row * 1024 + t * 4);
    float s1 = v.x + v.y + v.z + v.w;
    float s2 = v.x * v.x + v.y * v.y + v.z * v.z + v.w * v.w;
#pragma unroll
    for (int m = 1; m < 64; m <<= 1) {
        s1 += __shfl_xor(s1, m);
        s2 += __shfl_xor(s2, m);
    }
    __shared__ float red[8];
    if ((t & 63) == 0) { red[(t >> 6) * 2] = s1; red[(t >> 6) * 2 + 1] = s2; }
    __syncthreads();
    s1 = red[0] + red[2] + red[4] + red[6];
    s2 = red[1] + red[3] + red[5] + red[7];
    const float mu = s1 * (1.0f / 1024.0f);
    const float inv = rsqrtf(s2 * (1.0f / 1024.0f) - mu * mu + 1e-5f);
    const float4 gg = *(const float4*)(gam + t * 4);
    const float4 bb = *(const float4*)(bet + t * 4);
    bf16x4 o;
    o[0] = (bf16_t)((v.x - mu) * inv * gg.x + bb.x);
    o[1] = (bf16_t)((v.y - mu) * inv * gg.y + bb.y);
    o[2] = (bf16_t)((v.z - mu) * inv * gg.z + bb.z);
    o[3] = (bf16_t)((v.w - mu) * inv * gg.w + bb.w);
    *(bf16x4*)(out + (size_t)row * 1024 + t * 4) = o;
}

// ---------------- GEMM: C[M][N] = A[M][K](bf16) * Bt[N][K](bf16) + bias
// EPI: 0 = bf16 out, 1 = gelu -> bf16 out, 2 = +res(fp32) -> fp32 out
template <int EPI>
__global__ __launch_bounds__(256) void gemm_bt(
    const bf16_t* __restrict__ A, const bf16_t* __restrict__ Bt,
    const float* __restrict__ bias, const float* __restrict__ res,
    bf16_t* __restrict__ outb, float* __restrict__ outf,
    int M, int N, int K)
{
    __shared__ alignas(1024) bf16_t Alds[128 * 32];
    __shared__ alignas(1024) bf16_t Blds[128 * 32];
    const int t = threadIdx.x;
    const int lane = t & 63, w = t >> 6;
    const int wr = w >> 1, wc = w & 1;
    const int m0 = blockIdx.y * 128, n0 = blockIdx.x * 128;
    const int g = lane >> 4, ci = lane & 15;

    f32x4 acc[4][4];
#pragma unroll
    for (int i = 0; i < 4; ++i)
#pragma unroll
        for (int j = 0; j < 4; ++j)
#pragma unroll
            for (int k = 0; k < 4; ++k) acc[i][j][k] = 0.0f;

    const int r0 = t >> 2;             // staging row (issue 0), 4 chunks/row
    const int cc = (t & 3) * 8;        // staging col (elements)
    char* aB = (char*)Alds + w * 1024;
    char* bB = (char*)Blds + w * 1024;
    const int nkt = K >> 5;
    for (int kt = 0; kt < nkt; ++kt) {
        const int kk = kt * 32;
        gload_lds16(A + (size_t)(m0 + r0) * K + kk + cc, aB);
        gload_lds16(A + (size_t)(m0 + r0 + 64) * K + kk + cc, aB + 4096);
        gload_lds16(Bt + (size_t)(n0 + r0) * K + kk + cc, bB);
        gload_lds16(Bt + (size_t)(n0 + r0 + 64) * K + kk + cc, bB + 4096);
        __syncthreads();
        const bf16_t* ap = Alds + (wr * 64 + ci) * 32 + g * 8;
        const bf16_t* bp = Blds + (wc * 64 + ci) * 32 + g * 8;
        bf16x8 af[4], bf[4];
#pragma unroll
        for (int mt = 0; mt < 4; ++mt) af[mt] = *(const bf16x8*)(ap + mt * 16 * 32);
#pragma unroll
        for (int nt = 0; nt < 4; ++nt) bf[nt] = *(const bf16x8*)(bp + nt * 16 * 32);
#pragma unroll
        for (int mt = 0; mt < 4; ++mt)
#pragma unroll
            for (int nt = 0; nt < 4; ++nt)
                acc[mt][nt] = mfma16(af[mt], bf[nt], acc[mt][nt]);
        __syncthreads();
    }

#pragma unroll
    for (int nt = 0; nt < 4; ++nt) {
        const int col = n0 + wc * 64 + nt * 16 + ci;
        const float bv = bias[col];
#pragma unroll
        for (int mt = 0; mt < 4; ++mt) {
            const int row = m0 + wr * 64 + mt * 16 + g * 4;
#pragma unroll
            for (int r = 0; r < 4; ++r) {
                float v = acc[mt][nt][r] + bv;
                if constexpr (EPI == 1) v = gelu_exact(v);
                if constexpr (EPI == 2) {
                    outf[(size_t)(row + r) * N + col] =
                        v + res[(size_t)(row + r) * N + col];
                } else {
                    outb[(size_t)(row + r) * N + col] = (bf16_t)v;
                }
            }
        }
    }
}

// ---------------- causal flash attention
// qkv bf16 [T][3072] (Q at h*64, K at 1024+h*64, V at 2048+h*64)
// vt  bf16 [H][64][T]  (V transposed per head)
// out bf16 [T][1024]   ([t][h*64+d])
// grid (h=16, by=64); by remapped to qt so each CU's 4 blocks sum to equal work.
// K/V LDS tiles are XOR-swizzled: LDS stays lane-linear (global_load_lds
// requirement); the per-lane GLOBAL source chunk is pre-swizzled (chunk ^= row&7),
// and reads apply the same XOR -> b128 reads hit the 8-access/bank floor.
__global__ __launch_bounds__(256) void attn_fwd(
    const bf16_t* __restrict__ qkv, const bf16_t* __restrict__ vt,
    bf16_t* __restrict__ out)
{
    __shared__ alignas(1024) bf16_t Klds[64 * 64];
    __shared__ alignas(1024) bf16_t Vlds[64 * 64];   // [d][kpos] (swizzled)
    __shared__ alignas(1024) bf16_t Plds[4][16 * 72];
    const int t = threadIdx.x, lane = t & 63, w = t >> 6;
    const int g = lane >> 4, ci = lane & 15;
    const int h = blockIdx.x;
    // balanced qt mapping: CU c's 4 blocks get {2a, 63-2a, 2a+1, 62-2a}
    const int aa = blockIdx.y & 15, kk4 = blockIdx.y >> 4;
    const int qt = (kk4 & 1) ? (63 - 2 * aa - (kk4 >> 1)) : (2 * aa + (kk4 >> 1));
    const int q0 = qt * 64;

    const size_t qrow = (size_t)q0 + w * 16 + ci;
    const bf16x8 qf0 = *(const bf16x8*)(qkv + qrow * 3072 + h * 64 + g * 8);
    const bf16x8 qf1 = *(const bf16x8*)(qkv + qrow * 3072 + h * 64 + 32 + g * 8);

    f32x4 oacc[4];
#pragma unroll
    for (int dt = 0; dt < 4; ++dt)
#pragma unroll
        for (int r = 0; r < 4; ++r) oacc[dt][r] = 0.0f;
    float m_i[4] = {-1e30f, -1e30f, -1e30f, -1e30f};
    float l_i[4] = {0.0f, 0.0f, 0.0f, 0.0f};

    const int sr = t >> 3;                       // staging row, 8 chunks/row
    const int sx = ((t & 7) ^ (sr & 7)) * 8;     // swizzled source chunk (elems)
    char* kB = (char*)Klds + w * 1024;
    char* vB = (char*)Vlds + w * 1024;

    // swizzled read offsets (elements): chunk g and g+4 of row ci
    const int c0 = ((g ^ (ci & 7)) << 3);
    const int c1 = c0 ^ 32;

    for (int kt = 0; kt <= qt; ++kt) {
        const bf16_t* kg = qkv + (size_t)(kt * 64 + sr) * 3072 + 1024 + h * 64 + sx;
        gload_lds16(kg, kB);
        gload_lds16(kg + (size_t)32 * 3072, kB + 4096);
        const bf16_t* vg = vt + (size_t)h * (64 * 4096) + (size_t)sr * 4096 + kt * 64 + sx;
        gload_lds16(vg, vB);
        gload_lds16(vg + (size_t)32 * 4096, vB + 4096);
        __syncthreads();

        // S = Q K^T (per wave: 16 q-rows x 64 kpos)
        f32x4 s[4];
        const bf16_t* krow = Klds + ci * 64;
        __builtin_amdgcn_s_setprio(1);
#pragma unroll
        for (int nt = 0; nt < 4; ++nt) {
            f32x4 z;
#pragma unroll
            for (int k = 0; k < 4; ++k) z[k] = 0.0f;
            z = mfma16(qf0, *(const bf16x8*)(krow + nt * 1024 + c0), z);
            z = mfma16(qf1, *(const bf16x8*)(krow + nt * 1024 + c1), z);
            s[nt] = z;
        }
        __builtin_amdgcn_s_setprio(0);

        const bool diag = (kt == qt);
        float pm[4] = {-1e30f, -1e30f, -1e30f, -1e30f};
#pragma unroll
        for (int nt = 0; nt < 4; ++nt)
#pragma unroll
            for (int r = 0; r < 4; ++r) {
                float sv = s[nt][r] * 0.125f;
                if (diag && (nt * 16 + ci > w * 16 + g * 4 + r)) sv = -1e30f;
                s[nt][r] = sv;
                pm[r] = fmaxf(pm[r], sv);
            }
#pragma unroll
        for (int r = 0; r < 4; ++r)
#pragma unroll
            for (int m = 1; m < 16; m <<= 1)
                pm[r] = fmaxf(pm[r], __shfl_xor(pm[r], m));

        float newm[4], sc_[4], rs[4], ps[4][4];
#pragma unroll
        for (int r = 0; r < 4; ++r) { newm[r] = fmaxf(m_i[r], pm[r]); rs[r] = 0.0f; }
#pragma unroll
        for (int nt = 0; nt < 4; ++nt)
#pragma unroll
            for (int r = 0; r < 4; ++r) {
                float p = exp2f((s[nt][r] - newm[r]) * 1.4426950408889634f);
                ps[nt][r] = p;
                rs[r] += p;
            }
#pragma unroll
        for (int r = 0; r < 4; ++r) {
#pragma unroll
            for (int m = 1; m < 16; m <<= 1) rs[r] += __shfl_xor(rs[r], m);
            sc_[r] = exp2f((m_i[r] - newm[r]) * 1.4426950408889634f);
            l_i[r] = l_i[r] * sc_[r] + rs[r];
            m_i[r] = newm[r];
        }
#pragma unroll
        for (int dt = 0; dt < 4; ++dt)
#pragma unroll
            for (int r = 0; r < 4; ++r) oacc[dt][r] *= sc_[r];

        // P -> LDS (per-wave buffer), reshape into A-fragments
        bf16_t* pl = &Plds[w][0];
#pragma unroll
        for (int nt = 0; nt < 4; ++nt)
#pragma unroll
            for (int r = 0; r < 4; ++r)
                pl[(g * 4 + r) * 72 + nt * 16 + ci] = (bf16_t)ps[nt][r];
        asm volatile("s_waitcnt lgkmcnt(0)" ::: "memory");
        __builtin_amdgcn_sched_barrier(0);

        const bf16_t* pp = pl + ci * 72;
        const bf16x8 pf0 = *(const bf16x8*)(pp + g * 8);
        const bf16x8 pf1 = *(const bf16x8*)(pp + 32 + g * 8);
        const bf16_t* vrow = Vlds + ci * 64;
        __builtin_amdgcn_s_setprio(1);
#pragma unroll
        for (int dt = 0; dt < 4; ++dt) {
            oacc[dt] = mfma16(pf0, *(const bf16x8*)(vrow + dt * 1024 + c0), oacc[dt]);
            oacc[dt] = mfma16(pf1, *(const bf16x8*)(vrow + dt * 1024 + c1), oacc[dt]);
        }
        __builtin_amdgcn_s_setprio(0);
        __syncthreads();
    }

#pragma unroll
    for (int r = 0; r < 4; ++r) {
        const float inv = 1.0f / l_i[r];
        const size_t row = (size_t)q0 + w * 16 + g * 4 + r;
#pragma unroll
        for (int dt = 0; dt < 4; ++dt)
            out[row * 1024 + h * 64 + dt * 16 + ci] = (bf16_t)(oacc[dt][r] * inv);
    }
}

extern "C" void kernel_launch(void* const* d_in, const int* in_sizes, int n_in,
                              void* d_out, int out_size, void* d_ws, size_t ws_size,
                              hipStream_t stream)
{
    const float* x    = (const float*)d_in[0];
    const float* ln1g = (const float*)d_in[1];
    const float* ln1b = (const float*)d_in[2];
    const float* Wqkv = (const float*)d_in[3];
    const float* bqkv = (const float*)d_in[4];
    const float* Wo   = (const float*)d_in[5];
    const float* bo   = (const float*)d_in[6];
    const float* ln2g = (const float*)d_in[7];
    const float* ln2b = (const float*)d_in[8];
    const float* W1   = (const float*)d_in[9];
    const float* b1   = (const float*)d_in[10];
    const float* W2   = (const float*)d_in[11];
    const float* b2   = (const float*)d_in[12];
    float* outp = (float*)d_out;

    char* p = (char*)d_ws;
    bf16_t* WqkvT = (bf16_t*)p; p += (size_t)3072 * 1024 * 2;
    bf16_t* WoT   = (bf16_t*)p; p += (size_t)1024 * 1024 * 2;
    bf16_t* W1T   = (bf16_t*)p; p += (size_t)4096 * 1024 * 2;
    bf16_t* W2T   = (bf16_t*)p; p += (size_t)1024 * 4096 * 2;
    bf16_t* xn    = (bf16_t*)p; p += (size_t)4096 * 1024 * 2;
    bf16_t* qkv   = (bf16_t*)p; p += (size_t)4096 * 3072 * 2;
    bf16_t* vtb   = (bf16_t*)p; p += (size_t)16 * 64 * 4096 * 2;
    bf16_t* attnb = (bf16_t*)p; p += (size_t)4096 * 1024 * 2;
    float*  x2    = (float*)p;  p += (size_t)4096 * 1024 * 4;
    bf16_t* hb    = (bf16_t*)p; p += (size_t)4096 * 1024 * 2;
    bf16_t* g1    = (bf16_t*)p; p += (size_t)4096 * 4096 * 2;

    const dim3 tb(32, 8);
    transpose_w<<<dim3(96, 32),  tb, 0, stream>>>(Wqkv, WqkvT, 1024, 3072);
    transpose_w<<<dim3(32, 32),  tb, 0, stream>>>(Wo,   WoT,   1024, 1024);
    transpose_w<<<dim3(128, 32), tb, 0, stream>>>(W1,   W1T,   1024, 4096);
    transpose_w<<<dim3(32, 128), tb, 0, stream>>>(W2,   W2T,   4096, 1024);

    ln_bf16<<<4096, 256, 0, stream>>>(x, ln1g, ln1b, xn);
    gemm_bt<0><<<dim3(24, 32), 256, 0, stream>>>(xn, WqkvT, bqkv, nullptr,
                                                 qkv, nullptr, 4096, 3072, 1024);
    vtrans<<<dim3(128, 2, 16), tb, 0, stream>>>(qkv, vtb);
    attn_fwd<<<dim3(16, 64), 256, 0, stream>>>(qkv, vtb, attnb);
    gemm_bt<2><<<dim3(8, 32), 256, 0, stream>>>(attnb, WoT, bo, x,
                                                nullptr, x2, 4096, 1024, 1024);
    ln_bf16<<<4096, 256, 0, stream>>>(x2, ln2g, ln2b, hb);
    gemm_bt<1><<<dim3(32, 32), 256, 0, stream>>>(hb, W1T, b1, nullptr,
                                                 g1, nullptr, 4096, 4096, 1024);
    gemm_bt<2><<<dim3(8, 32), 256, 0, stream>>>(g1, W2T, b2, x2,
                                                nullptr, outp, 4096, 1024, 4096);
}

// Round 3
// 367.861 us; speedup vs baseline: 1.4555x; 1.0597x over previous
//
#include <hip/hip_runtime.h>
#include <math.h>

typedef __bf16 bf16_t;
typedef __attribute__((ext_vector_type(8))) __bf16 bf16x8;
typedef __attribute__((ext_vector_type(4))) __bf16 bf16x4;
typedef __attribute__((ext_vector_type(4))) float f32x4;

#define T_LEN 4096
#define C_DIM 1024
#define NH 16
#define HD 64

__device__ __forceinline__ void gload_lds16(const void* g, void* l) {
    __builtin_amdgcn_global_load_lds(
        (__attribute__((address_space(1))) void*)(g),
        (__attribute__((address_space(3))) void*)(l), 16, 0, 0);
}

__device__ __forceinline__ f32x4 mfma16(bf16x8 a, bf16x8 b, f32x4 c) {
    return __builtin_amdgcn_mfma_f32_16x16x32_bf16(a, b, c, 0, 0, 0);
}

__device__ __forceinline__ float gelu_exact(float v) {
    return 0.5f * v * (1.0f + erff(v * 0.7071067811865476f));
}

// ---------------- weight transpose+convert: in fp32 [R][C] -> out bf16 [C][R]
__global__ __launch_bounds__(256) void transpose_w(
    const float* __restrict__ in, bf16_t* __restrict__ out, int R, int C)
{
    __shared__ float tile[32][33];
    const int tx = threadIdx.x, ty = threadIdx.y;
    const int c0 = blockIdx.x * 32, r0 = blockIdx.y * 32;
#pragma unroll
    for (int j = 0; j < 4; ++j)
        tile[ty + j * 8][tx] = in[(size_t)(r0 + ty + j * 8) * C + c0 + tx];
    __syncthreads();
#pragma unroll
    for (int j = 0; j < 4; ++j)
        out[(size_t)(c0 + ty + j * 8) * R + r0 + tx] = (bf16_t)tile[tx][ty + j * 8];
}

// ---------------- per-head V transpose: qkv bf16 [T][3C] -> vt [H][64][T]
__global__ __launch_bounds__(256) void vtrans(
    const bf16_t* __restrict__ qkv, bf16_t* __restrict__ vt)
{
    __shared__ bf16_t tile[32][33];
    const int tx = threadIdx.x, ty = threadIdx.y;
    const int h = blockIdx.z;
    const int t0 = blockIdx.x * 32, d0 = blockIdx.y * 32;
#pragma unroll
    for (int j = 0; j < 4; ++j)
        tile[ty + j * 8][tx] =
            qkv[(size_t)(t0 + ty + j * 8) * 3072 + 2048 + h * 64 + d0 + tx];
    __syncthreads();
#pragma unroll
    for (int j = 0; j < 4; ++j)
        vt[(size_t)h * (64 * 4096) + (size_t)(d0 + ty + j * 8) * 4096 + t0 + tx] =
            tile[tx][ty + j * 8];
}

// ---------------- LayerNorm fp32 -> bf16
__global__ __launch_bounds__(256) void ln_bf16(
    const float* __restrict__ x, const float* __restrict__ gam,
    const float* __restrict__ bet, bf16_t* __restrict__ out)
{
    const int row = blockIdx.x, t = threadIdx.x;
    const float4 v = *(const float4*)(x + (size_t)row * 1024 + t * 4);
    float s1 = v.x + v.y + v.z + v.w;
    float s2 = v.x * v.x + v.y * v.y + v.z * v.z + v.w * v.w;
#pragma unroll
    for (int m = 1; m < 64; m <<= 1) {
        s1 += __shfl_xor(s1, m);
        s2 += __shfl_xor(s2, m);
    }
    __shared__ float red[8];
    if ((t & 63) == 0) { red[(t >> 6) * 2] = s1; red[(t >> 6) * 2 + 1] = s2; }
    __syncthreads();
    s1 = red[0] + red[2] + red[4] + red[6];
    s2 = red[1] + red[3] + red[5] + red[7];
    const float mu = s1 * (1.0f / 1024.0f);
    const float inv = rsqrtf(s2 * (1.0f / 1024.0f) - mu * mu + 1e-5f);
    const float4 gg = *(const float4*)(gam + t * 4);
    const float4 bb = *(const float4*)(bet + t * 4);
    bf16x4 o;
    o[0] = (bf16_t)((v.x - mu) * inv * gg.x + bb.x);
    o[1] = (bf16_t)((v.y - mu) * inv * gg.y + bb.y);
    o[2] = (bf16_t)((v.z - mu) * inv * gg.z + bb.z);
    o[3] = (bf16_t)((v.w - mu) * inv * gg.w + bb.w);
    *(bf16x4*)(out + (size_t)row * 1024 + t * 4) = o;
}

// ---------------- 128x128 GEMM (m97 structure), for N=1024 shapes
// EPI: 0 = bf16 out, 1 = gelu -> bf16 out, 2 = +res(fp32) -> fp32 out
template <int EPI>
__global__ __launch_bounds__(256) void gemm_bt(
    const bf16_t* __restrict__ A, const bf16_t* __restrict__ Bt,
    const float* __restrict__ bias, const float* __restrict__ res,
    bf16_t* __restrict__ outb, float* __restrict__ outf,
    int M, int N, int K)
{
    __shared__ alignas(1024) bf16_t Alds[128 * 32];
    __shared__ alignas(1024) bf16_t Blds[128 * 32];
    const int t = threadIdx.x;
    const int lane = t & 63, w = t >> 6;
    const int wr = w >> 1, wc = w & 1;
    const int m0 = blockIdx.y * 128, n0 = blockIdx.x * 128;
    const int g = lane >> 4, ci = lane & 15;

    f32x4 acc[4][4];
#pragma unroll
    for (int i = 0; i < 4; ++i)
#pragma unroll
        for (int j = 0; j < 4; ++j)
#pragma unroll
            for (int k = 0; k < 4; ++k) acc[i][j][k] = 0.0f;

    const int r0 = t >> 2;
    const int cc = (t & 3) * 8;
    char* aB = (char*)Alds + w * 1024;
    char* bB = (char*)Blds + w * 1024;
    const int nkt = K >> 5;
    for (int kt = 0; kt < nkt; ++kt) {
        const int kk = kt * 32;
        gload_lds16(A + (size_t)(m0 + r0) * K + kk + cc, aB);
        gload_lds16(A + (size_t)(m0 + r0 + 64) * K + kk + cc, aB + 4096);
        gload_lds16(Bt + (size_t)(n0 + r0) * K + kk + cc, bB);
        gload_lds16(Bt + (size_t)(n0 + r0 + 64) * K + kk + cc, bB + 4096);
        __syncthreads();
        const bf16_t* ap = Alds + (wr * 64 + ci) * 32 + g * 8;
        const bf16_t* bp = Blds + (wc * 64 + ci) * 32 + g * 8;
        bf16x8 af[4], bf[4];
#pragma unroll
        for (int mt = 0; mt < 4; ++mt) af[mt] = *(const bf16x8*)(ap + mt * 16 * 32);
#pragma unroll
        for (int nt = 0; nt < 4; ++nt) bf[nt] = *(const bf16x8*)(bp + nt * 16 * 32);
#pragma unroll
        for (int mt = 0; mt < 4; ++mt)
#pragma unroll
            for (int nt = 0; nt < 4; ++nt)
                acc[mt][nt] = mfma16(af[mt], bf[nt], acc[mt][nt]);
        __syncthreads();
    }

#pragma unroll
    for (int nt = 0; nt < 4; ++nt) {
        const int col = n0 + wc * 64 + nt * 16 + ci;
        const float bv = bias[col];
#pragma unroll
        for (int mt = 0; mt < 4; ++mt) {
            const int row = m0 + wr * 64 + mt * 16 + g * 4;
#pragma unroll
            for (int r = 0; r < 4; ++r) {
                float v = acc[mt][nt][r] + bv;
                if constexpr (EPI == 1) v = gelu_exact(v);
                if constexpr (EPI == 2) {
                    outf[(size_t)(row + r) * N + col] =
                        v + res[(size_t)(row + r) * N + col];
                } else {
                    outb[(size_t)(row + r) * N + col] = (bf16_t)v;
                }
            }
        }
    }
}

// ---------------- 256x256 8-phase GEMM (m201 structure: T2+T3+T4+T5)
// C[M][N] = A[M][K] * Bt[N][K] + bias; EPI: 0 = bf16, 1 = gelu->bf16.
// 8 waves (2M x 4N); wave (wr,wc) owns rows {wr*64..+63, 128+wr*64..+63} x
// cols {wc*32..+31, 128+wc*32..+31} so phase p reads exactly one half-tile
// region (A0/B0/B1/A1), making stage-into-consumed-buffer barrier-safe.
// LDS: 2 buf x (A 256x64 + B 256x64) bf16 = 128 KiB. XOR swizzle chunk^=row&7
// on both stage-source and ds_read. Counted vmcnt(6) per K-tile (T4).
template <int EPI>
__global__ __launch_bounds__(512, 2) void gemm256(
    const bf16_t* __restrict__ A, const bf16_t* __restrict__ Bt,
    const float* __restrict__ bias, bf16_t* __restrict__ outb,
    int M, int N, int K)
{
    __shared__ alignas(1024) bf16_t lds[2][2][256 * 64];
    const int t = threadIdx.x, lane = t & 63, w = t >> 6;
    const int g = lane >> 4, ci = lane & 15;
    const int wr = w >> 2, wc = w & 3;
    const int m0 = blockIdx.y * 256, n0 = blockIdx.x * 256;
    const int NKT = K >> 6;

    f32x4 acc[8][4];
#pragma unroll
    for (int i = 0; i < 8; ++i)
#pragma unroll
        for (int j = 0; j < 4; ++j)
#pragma unroll
            for (int k2 = 0; k2 < 4; ++k2) acc[i][j][k2] = 0.0f;

    const int sw0 = (g ^ (ci & 7)) * 8;        // elem offset, kk=0 chunk
    const int sw1 = ((4 + g) ^ (ci & 7)) * 8;  // elem offset, kk=1 chunk

    // stage half-tile h (0=A0,1=A1,2=B0,3=B1) of K-tile kt into buffer b.
    // LDS linear dest (wave-uniform base + lane*16); global source chunk
    // pre-swizzled c = (t&7) ^ (r&7).
    auto stage = [&](int h, int ktile, int b) {
#pragma unroll
        for (int i = 0; i < 2; ++i) {
            const int idx = i * 512 + t;
            const int r = idx >> 3;
            const int c = (t & 7) ^ (r & 7);
            const bf16_t* src = ((h < 2) ? A : Bt)
                + (size_t)(((h < 2) ? m0 : n0) + (h & 1) * 128 + r) * K
                + ktile * 64 + c * 8;
            bf16_t* dst = &lds[b][h >> 1][(h & 1) * 8192] + (i * 512 + w * 64) * 8;
            gload_lds16(src, dst);
        }
    };

    bf16x8 a[4][2], b2[2][2][2];

    // prologue: tile0 {A0,B1,A1,B0}, tile1 {A0,B1,A1}; wait tile0 (8 oldest)
    stage(0, 0, 0); stage(3, 0, 0); stage(1, 0, 0); stage(2, 0, 0);
    if (NKT > 1) { stage(0, 1, 1); stage(3, 1, 1); stage(1, 1, 1); }
    asm volatile("s_waitcnt vmcnt(6)" ::: "memory");
    __builtin_amdgcn_s_barrier();

    for (int kt = 0; kt < NKT; ++kt) {
        const int cur = kt & 1;
        const bf16_t* Ab = &lds[cur][0][0];
        const bf16_t* Bb = &lds[cur][1][0];

        // ---- phase 0: read A-half0 + B-half0; stage (kt+1).B0 -> other buf
#pragma unroll
        for (int mi = 0; mi < 4; ++mi) {
            const bf16_t* ap = Ab + (wr * 64 + mi * 16 + ci) * 64;
            a[mi][0] = *(const bf16x8*)(ap + sw0);
            a[mi][1] = *(const bf16x8*)(ap + sw1);
        }
#pragma unroll
        for (int ni = 0; ni < 2; ++ni) {
            const bf16_t* bp = Bb + (wc * 32 + ni * 16 + ci) * 64;
            b2[0][ni][0] = *(const bf16x8*)(bp + sw0);
            b2[0][ni][1] = *(const bf16x8*)(bp + sw1);
        }
        if (kt + 1 < NKT) stage(2, kt + 1, cur ^ 1);
        __builtin_amdgcn_s_barrier();
        asm volatile("s_waitcnt lgkmcnt(0)" ::: "memory");
        __builtin_amdgcn_sched_barrier(0);
        __builtin_amdgcn_s_setprio(1);
#pragma unroll
        for (int mi = 0; mi < 4; ++mi)
#pragma unroll
            for (int ni = 0; ni < 2; ++ni) {
                acc[mi][ni] = mfma16(a[mi][0], b2[0][ni][0], acc[mi][ni]);
                acc[mi][ni] = mfma16(a[mi][1], b2[0][ni][1], acc[mi][ni]);
            }
        __builtin_amdgcn_s_setprio(0);
        __builtin_amdgcn_s_barrier();

        // ---- phase 1: read B-half1; stage (kt+2).A0 -> cur buf
#pragma unroll
        for (int ni = 0; ni < 2; ++ni) {
            const bf16_t* bp = Bb + (128 + wc * 32 + ni * 16 + ci) * 64;
            b2[1][ni][0] = *(const bf16x8*)(bp + sw0);
            b2[1][ni][1] = *(const bf16x8*)(bp + sw1);
        }
        if (kt + 2 < NKT) stage(0, kt + 2, cur);
        __builtin_amdgcn_s_barrier();
        asm volatile("s_waitcnt lgkmcnt(0)" ::: "memory");
        __builtin_amdgcn_sched_barrier(0);
        __builtin_amdgcn_s_setprio(1);
#pragma unroll
        for (int mi = 0; mi < 4; ++mi)
#pragma unroll
            for (int ni = 0; ni < 2; ++ni) {
                acc[mi][2 + ni] = mfma16(a[mi][0], b2[1][ni][0], acc[mi][2 + ni]);
                acc[mi][2 + ni] = mfma16(a[mi][1], b2[1][ni][1], acc[mi][2 + ni]);
            }
        __builtin_amdgcn_s_setprio(0);
        __builtin_amdgcn_s_barrier();

        // ---- phase 2: read A-half1; stage (kt+2).B1 -> cur buf
#pragma unroll
        for (int mi = 0; mi < 4; ++mi) {
            const bf16_t* ap = Ab + (128 + wr * 64 + mi * 16 + ci) * 64;
            a[mi][0] = *(const bf16x8*)(ap + sw0);
            a[mi][1] = *(const bf16x8*)(ap + sw1);
        }
        if (kt + 2 < NKT) stage(3, kt + 2, cur);
        __builtin_amdgcn_s_barrier();
        asm volatile("s_waitcnt lgkmcnt(0)" ::: "memory");
        __builtin_amdgcn_sched_barrier(0);
        __builtin_amdgcn_s_setprio(1);
#pragma unroll
        for (int mi = 0; mi < 4; ++mi)
#pragma unroll
            for (int ni = 0; ni < 2; ++ni) {
                acc[4 + mi][2 + ni] = mfma16(a[mi][0], b2[1][ni][0], acc[4 + mi][2 + ni]);
                acc[4 + mi][2 + ni] = mfma16(a[mi][1], b2[1][ni][1], acc[4 + mi][2 + ni]);
            }
        __builtin_amdgcn_s_setprio(0);
        __builtin_amdgcn_s_barrier();

        // ---- phase 3: stage (kt+2).A1 -> cur buf; MFMA A1 x B0; counted vmcnt
        if (kt + 2 < NKT) stage(1, kt + 2, cur);
        __builtin_amdgcn_s_barrier();
        __builtin_amdgcn_s_setprio(1);
#pragma unroll
        for (int mi = 0; mi < 4; ++mi)
#pragma unroll
            for (int ni = 0; ni < 2; ++ni) {
                acc[4 + mi][ni] = mfma16(a[mi][0], b2[0][ni][0], acc[4 + mi][ni]);
                acc[4 + mi][ni] = mfma16(a[mi][1], b2[0][ni][1], acc[4 + mi][ni]);
            }
        __builtin_amdgcn_s_setprio(0);
        if (kt + 2 < NKT) asm volatile("s_waitcnt vmcnt(6)" ::: "memory");
        else              asm volatile("s_waitcnt vmcnt(0)" ::: "memory");
        __builtin_amdgcn_s_barrier();
    }

#pragma unroll
    for (int mrep = 0; mrep < 8; ++mrep) {
        const int row = m0 + (mrep >> 2) * 128 + wr * 64 + (mrep & 3) * 16 + g * 4;
#pragma unroll
        for (int nrep = 0; nrep < 4; ++nrep) {
            const int col = n0 + (nrep >> 1) * 128 + wc * 32 + (nrep & 1) * 16 + ci;
            const float bv = bias[col];
#pragma unroll
            for (int jr = 0; jr < 4; ++jr) {
                float v = acc[mrep][nrep][jr] + bv;
                if constexpr (EPI == 1) v = gelu_exact(v);
                outb[(size_t)(row + jr) * N + col] = (bf16_t)v;
            }
        }
    }
}

// ---------------- causal flash attention
__global__ __launch_bounds__(256) void attn_fwd(
    const bf16_t* __restrict__ qkv, const bf16_t* __restrict__ vt,
    bf16_t* __restrict__ out)
{
    __shared__ alignas(1024) bf16_t Klds[64 * 64];
    __shared__ alignas(1024) bf16_t Vlds[64 * 64];
    __shared__ alignas(1024) bf16_t Plds[4][16 * 72];
    const int t = threadIdx.x, lane = t & 63, w = t >> 6;
    const int g = lane >> 4, ci = lane & 15;
    const int h = blockIdx.x;
    const int aa = blockIdx.y & 15, kk4 = blockIdx.y >> 4;
    const int qt = (kk4 & 1) ? (63 - 2 * aa - (kk4 >> 1)) : (2 * aa + (kk4 >> 1));
    const int q0 = qt * 64;
    // score scale folded with log2e: p = exp2(s*C1 - m')
    const float C1 = 0.125f * 1.4426950408889634f;

    const size_t qrow = (size_t)q0 + w * 16 + ci;
    const bf16x8 qf0 = *(const bf16x8*)(qkv + qrow * 3072 + h * 64 + g * 8);
    const bf16x8 qf1 = *(const bf16x8*)(qkv + qrow * 3072 + h * 64 + 32 + g * 8);

    f32x4 oacc[4];
#pragma unroll
    for (int dt = 0; dt < 4; ++dt)
#pragma unroll
        for (int r = 0; r < 4; ++r) oacc[dt][r] = 0.0f;
    float m_i[4] = {-1e30f, -1e30f, -1e30f, -1e30f};
    float l_i[4] = {0.0f, 0.0f, 0.0f, 0.0f};

    const int sr = t >> 3;
    const int sx = ((t & 7) ^ (sr & 7)) * 8;
    char* kB = (char*)Klds + w * 1024;
    char* vB = (char*)Vlds + w * 1024;

    const int c0 = ((g ^ (ci & 7)) << 3);
    const int c1 = c0 ^ 32;

    for (int kt = 0; kt <= qt; ++kt) {
        const bf16_t* kg = qkv + (size_t)(kt * 64 + sr) * 3072 + 1024 + h * 64 + sx;
        gload_lds16(kg, kB);
        gload_lds16(kg + (size_t)32 * 3072, kB + 4096);
        const bf16_t* vg = vt + (size_t)h * (64 * 4096) + (size_t)sr * 4096 + kt * 64 + sx;
        gload_lds16(vg, vB);
        gload_lds16(vg + (size_t)32 * 4096, vB + 4096);
        __syncthreads();

        f32x4 s[4];
        const bf16_t* krow = Klds + ci * 64;
        __builtin_amdgcn_s_setprio(1);
#pragma unroll
        for (int nt = 0; nt < 4; ++nt) {
            f32x4 z;
#pragma unroll
            for (int k = 0; k < 4; ++k) z[k] = 0.0f;
            z = mfma16(qf0, *(const bf16x8*)(krow + nt * 1024 + c0), z);
            z = mfma16(qf1, *(const bf16x8*)(krow + nt * 1024 + c1), z);
            s[nt] = z;
        }
        __builtin_amdgcn_s_setprio(0);

        const bool diag = (kt == qt);
        float pm[4] = {-1e30f, -1e30f, -1e30f, -1e30f};
#pragma unroll
        for (int nt = 0; nt < 4; ++nt)
#pragma unroll
            for (int r = 0; r < 4; ++r) {
                float sv = s[nt][r] * C1;
                if (diag && (nt * 16 + ci > w * 16 + g * 4 + r)) sv = -1e30f;
                s[nt][r] = sv;
                pm[r] = fmaxf(pm[r], sv);
            }
#pragma unroll
        for (int r = 0; r < 4; ++r)
#pragma unroll
            for (int m = 1; m < 16; m <<= 1)
                pm[r] = fmaxf(pm[r], __shfl_xor(pm[r], m));

        float newm[4], sc_[4], rs[4], ps[4][4];
#pragma unroll
        for (int r = 0; r < 4; ++r) { newm[r] = fmaxf(m_i[r], pm[r]); rs[r] = 0.0f; }
#pragma unroll
        for (int nt = 0; nt < 4; ++nt)
#pragma unroll
            for (int r = 0; r < 4; ++r) {
                float p = exp2f(s[nt][r] - newm[r]);
                ps[nt][r] = p;
                rs[r] += p;
            }
#pragma unroll
        for (int r = 0; r < 4; ++r) {
#pragma unroll
            for (int m = 1; m < 16; m <<= 1) rs[r] += __shfl_xor(rs[r], m);
            sc_[r] = exp2f(m_i[r] - newm[r]);
            l_i[r] = l_i[r] * sc_[r] + rs[r];
            m_i[r] = newm[r];
        }
#pragma unroll
        for (int dt = 0; dt < 4; ++dt)
#pragma unroll
            for (int r = 0; r < 4; ++r) oacc[dt][r] *= sc_[r];

        bf16_t* pl = &Plds[w][0];
#pragma unroll
        for (int nt = 0; nt < 4; ++nt)
#pragma unroll
            for (int r = 0; r < 4; ++r)
                pl[(g * 4 + r) * 72 + nt * 16 + ci] = (bf16_t)ps[nt][r];
        asm volatile("s_waitcnt lgkmcnt(0)" ::: "memory");
        __builtin_amdgcn_sched_barrier(0);

        const bf16_t* pp = pl + ci * 72;
        const bf16x8 pf0 = *(const bf16x8*)(pp + g * 8);
        const bf16x8 pf1 = *(const bf16x8*)(pp + 32 + g * 8);
        const bf16_t* vrow = Vlds + ci * 64;
        __builtin_amdgcn_s_setprio(1);
#pragma unroll
        for (int dt = 0; dt < 4; ++dt) {
            oacc[dt] = mfma16(pf0, *(const bf16x8*)(vrow + dt * 1024 + c0), oacc[dt]);
            oacc[dt] = mfma16(pf1, *(const bf16x8*)(vrow + dt * 1024 + c1), oacc[dt]);
        }
        __builtin_amdgcn_s_setprio(0);
        __syncthreads();
    }

#pragma unroll
    for (int r = 0; r < 4; ++r) {
        const float inv = 1.0f / l_i[r];
        const size_t row = (size_t)q0 + w * 16 + g * 4 + r;
#pragma unroll
        for (int dt = 0; dt < 4; ++dt)
            out[row * 1024 + h * 64 + dt * 16 + ci] = (bf16_t)(oacc[dt][r] * inv);
    }
}

extern "C" void kernel_launch(void* const* d_in, const int* in_sizes, int n_in,
                              void* d_out, int out_size, void* d_ws, size_t ws_size,
                              hipStream_t stream)
{
    const float* x    = (const float*)d_in[0];
    const float* ln1g = (const float*)d_in[1];
    const float* ln1b = (const float*)d_in[2];
    const float* Wqkv = (const float*)d_in[3];
    const float* bqkv = (const float*)d_in[4];
    const float* Wo   = (const float*)d_in[5];
    const float* bo   = (const float*)d_in[6];
    const float* ln2g = (const float*)d_in[7];
    const float* ln2b = (const float*)d_in[8];
    const float* W1   = (const float*)d_in[9];
    const float* b1   = (const float*)d_in[10];
    const float* W2   = (const float*)d_in[11];
    const float* b2   = (const float*)d_in[12];
    float* outp = (float*)d_out;

    char* p = (char*)d_ws;
    bf16_t* WqkvT = (bf16_t*)p; p += (size_t)3072 * 1024 * 2;
    bf16_t* WoT   = (bf16_t*)p; p += (size_t)1024 * 1024 * 2;
    bf16_t* W1T   = (bf16_t*)p; p += (size_t)4096 * 1024 * 2;
    bf16_t* W2T   = (bf16_t*)p; p += (size_t)1024 * 4096 * 2;
    bf16_t* xn    = (bf16_t*)p; p += (size_t)4096 * 1024 * 2;
    bf16_t* qkv   = (bf16_t*)p; p += (size_t)4096 * 3072 * 2;
    bf16_t* vtb   = (bf16_t*)p; p += (size_t)16 * 64 * 4096 * 2;
    bf16_t* attnb = (bf16_t*)p; p += (size_t)4096 * 1024 * 2;
    float*  x2    = (float*)p;  p += (size_t)4096 * 1024 * 4;
    bf16_t* hb    = (bf16_t*)p; p += (size_t)4096 * 1024 * 2;
    bf16_t* g1    = (bf16_t*)p; p += (size_t)4096 * 4096 * 2;

    const dim3 tb(32, 8);
    transpose_w<<<dim3(96, 32),  tb, 0, stream>>>(Wqkv, WqkvT, 1024, 3072);
    transpose_w<<<dim3(32, 32),  tb, 0, stream>>>(Wo,   WoT,   1024, 1024);
    transpose_w<<<dim3(128, 32), tb, 0, stream>>>(W1,   W1T,   1024, 4096);
    transpose_w<<<dim3(32, 128), tb, 0, stream>>>(W2,   W2T,   4096, 1024);

    ln_bf16<<<4096, 256, 0, stream>>>(x, ln1g, ln1b, xn);
    gemm256<0><<<dim3(12, 16), 512, 0, stream>>>(xn, WqkvT, bqkv,
                                                 qkv, 4096, 3072, 1024);
    vtrans<<<dim3(128, 2, 16), tb, 0, stream>>>(qkv, vtb);
    attn_fwd<<<dim3(16, 64), 256, 0, stream>>>(qkv, vtb, attnb);
    gemm_bt<2><<<dim3(8, 32), 256, 0, stream>>>(attnb, WoT, bo, x,
                                                nullptr, x2, 4096, 1024, 1024);
    ln_bf16<<<4096, 256, 0, stream>>>(x2, ln2g, ln2b, hb);
    gemm256<1><<<dim3(16, 16), 512, 0, stream>>>(hb, W1T, b1,
                                                 g1, 4096, 4096, 1024);
    gemm_bt<2><<<dim3(8, 32), 256, 0, stream>>>(g1, W2T, b2, x2,
                                                nullptr, outp, 4096, 1024, 4096);
}

// Round 4
// 358.270 us; speedup vs baseline: 1.4945x; 1.0268x over previous
//
#include <hip/hip_runtime.h>
#include <math.h>

typedef __bf16 bf16_t;
typedef __attribute__((ext_vector_type(8))) __bf16 bf16x8;
typedef __attribute__((ext_vector_type(4))) __bf16 bf16x4;
typedef __attribute__((ext_vector_type(4))) float f32x4;
typedef __attribute__((ext_vector_type(16))) float f32x16;

#define T_LEN 4096
#define C_DIM 1024
#define NH 16
#define HD 64

__device__ __forceinline__ void gload_lds16(const void* g, void* l) {
    __builtin_amdgcn_global_load_lds(
        (__attribute__((address_space(1))) void*)(g),
        (__attribute__((address_space(3))) void*)(l), 16, 0, 0);
}

__device__ __forceinline__ f32x4 mfma16(bf16x8 a, bf16x8 b, f32x4 c) {
    return __builtin_amdgcn_mfma_f32_16x16x32_bf16(a, b, c, 0, 0, 0);
}

__device__ __forceinline__ f32x16 mfma32(bf16x8 a, bf16x8 b, f32x16 c) {
    return __builtin_amdgcn_mfma_f32_32x32x16_bf16(a, b, c, 0, 0, 0);
}

__device__ __forceinline__ float gelu_exact(float v) {
    return 0.5f * v * (1.0f + erff(v * 0.7071067811865476f));
}

// ---------------- weight transpose+convert: in fp32 [R][C] -> out bf16 [C][R]
__global__ __launch_bounds__(256) void transpose_w(
    const float* __restrict__ in, bf16_t* __restrict__ out, int R, int C)
{
    __shared__ float tile[32][33];
    const int tx = threadIdx.x, ty = threadIdx.y;
    const int c0 = blockIdx.x * 32, r0 = blockIdx.y * 32;
#pragma unroll
    for (int j = 0; j < 4; ++j)
        tile[ty + j * 8][tx] = in[(size_t)(r0 + ty + j * 8) * C + c0 + tx];
    __syncthreads();
#pragma unroll
    for (int j = 0; j < 4; ++j)
        out[(size_t)(c0 + ty + j * 8) * R + r0 + tx] = (bf16_t)tile[tx][ty + j * 8];
}

// ---------------- per-head V transpose: qkv bf16 [T][3C] -> vt [H][64][T]
__global__ __launch_bounds__(256) void vtrans(
    const bf16_t* __restrict__ qkv, bf16_t* __restrict__ vt)
{
    __shared__ bf16_t tile[32][33];
    const int tx = threadIdx.x, ty = threadIdx.y;
    const int h = blockIdx.z;
    const int t0 = blockIdx.x * 32, d0 = blockIdx.y * 32;
#pragma unroll
    for (int j = 0; j < 4; ++j)
        tile[ty + j * 8][tx] =
            qkv[(size_t)(t0 + ty + j * 8) * 3072 + 2048 + h * 64 + d0 + tx];
    __syncthreads();
#pragma unroll
    for (int j = 0; j < 4; ++j)
        vt[(size_t)h * (64 * 4096) + (size_t)(d0 + ty + j * 8) * 4096 + t0 + tx] =
            tile[tx][ty + j * 8];
}

// ---------------- LayerNorm fp32 -> bf16
__global__ __launch_bounds__(256) void ln_bf16(
    const float* __restrict__ x, const float* __restrict__ gam,
    const float* __restrict__ bet, bf16_t* __restrict__ out)
{
    const int row = blockIdx.x, t = threadIdx.x;
    const float4 v = *(const float4*)(x + (size_t)row * 1024 + t * 4);
    float s1 = v.x + v.y + v.z + v.w;
    float s2 = v.x * v.x + v.y * v.y + v.z * v.z + v.w * v.w;
#pragma unroll
    for (int m = 1; m < 64; m <<= 1) {
        s1 += __shfl_xor(s1, m);
        s2 += __shfl_xor(s2, m);
    }
    __shared__ float red[8];
    if ((t & 63) == 0) { red[(t >> 6) * 2] = s1; red[(t >> 6) * 2 + 1] = s2; }
    __syncthreads();
    s1 = red[0] + red[2] + red[4] + red[6];
    s2 = red[1] + red[3] + red[5] + red[7];
    const float mu = s1 * (1.0f / 1024.0f);
    const float inv = rsqrtf(s2 * (1.0f / 1024.0f) - mu * mu + 1e-5f);
    const float4 gg = *(const float4*)(gam + t * 4);
    const float4 bb = *(const float4*)(bet + t * 4);
    bf16x4 o;
    o[0] = (bf16_t)((v.x - mu) * inv * gg.x + bb.x);
    o[1] = (bf16_t)((v.y - mu) * inv * gg.y + bb.y);
    o[2] = (bf16_t)((v.z - mu) * inv * gg.z + bb.z);
    o[3] = (bf16_t)((v.w - mu) * inv * gg.w + bb.w);
    *(bf16x4*)(out + (size_t)row * 1024 + t * 4) = o;
}

// ---------------- 128x128 GEMM (m97 structure), for N=1024 shapes
// EPI: 0 = bf16 out, 1 = gelu -> bf16 out, 2 = +res(fp32) -> fp32 out
template <int EPI>
__global__ __launch_bounds__(256) void gemm_bt(
    const bf16_t* __restrict__ A, const bf16_t* __restrict__ Bt,
    const float* __restrict__ bias, const float* __restrict__ res,
    bf16_t* __restrict__ outb, float* __restrict__ outf,
    int M, int N, int K)
{
    __shared__ alignas(1024) bf16_t Alds[128 * 32];
    __shared__ alignas(1024) bf16_t Blds[128 * 32];
    const int t = threadIdx.x;
    const int lane = t & 63, w = t >> 6;
    const int wr = w >> 1, wc = w & 1;
    const int m0 = blockIdx.y * 128, n0 = blockIdx.x * 128;
    const int g = lane >> 4, ci = lane & 15;

    f32x4 acc[4][4];
#pragma unroll
    for (int i = 0; i < 4; ++i)
#pragma unroll
        for (int j = 0; j < 4; ++j)
#pragma unroll
            for (int k = 0; k < 4; ++k) acc[i][j][k] = 0.0f;

    const int r0 = t >> 2;
    const int cc = (t & 3) * 8;
    char* aB = (char*)Alds + w * 1024;
    char* bB = (char*)Blds + w * 1024;
    const int nkt = K >> 5;
    for (int kt = 0; kt < nkt; ++kt) {
        const int kk = kt * 32;
        gload_lds16(A + (size_t)(m0 + r0) * K + kk + cc, aB);
        gload_lds16(A + (size_t)(m0 + r0 + 64) * K + kk + cc, aB + 4096);
        gload_lds16(Bt + (size_t)(n0 + r0) * K + kk + cc, bB);
        gload_lds16(Bt + (size_t)(n0 + r0 + 64) * K + kk + cc, bB + 4096);
        __syncthreads();
        const bf16_t* ap = Alds + (wr * 64 + ci) * 32 + g * 8;
        const bf16_t* bp = Blds + (wc * 64 + ci) * 32 + g * 8;
        bf16x8 af[4], bf[4];
#pragma unroll
        for (int mt = 0; mt < 4; ++mt) af[mt] = *(const bf16x8*)(ap + mt * 16 * 32);
#pragma unroll
        for (int nt = 0; nt < 4; ++nt) bf[nt] = *(const bf16x8*)(bp + nt * 16 * 32);
#pragma unroll
        for (int mt = 0; mt < 4; ++mt)
#pragma unroll
            for (int nt = 0; nt < 4; ++nt)
                acc[mt][nt] = mfma16(af[mt], bf[nt], acc[mt][nt]);
        __syncthreads();
    }

#pragma unroll
    for (int nt = 0; nt < 4; ++nt) {
        const int col = n0 + wc * 64 + nt * 16 + ci;
        const float bv = bias[col];
#pragma unroll
        for (int mt = 0; mt < 4; ++mt) {
            const int row = m0 + wr * 64 + mt * 16 + g * 4;
#pragma unroll
            for (int r = 0; r < 4; ++r) {
                float v = acc[mt][nt][r] + bv;
                if constexpr (EPI == 1) v = gelu_exact(v);
                if constexpr (EPI == 2) {
                    outf[(size_t)(row + r) * N + col] =
                        v + res[(size_t)(row + r) * N + col];
                } else {
                    outb[(size_t)(row + r) * N + col] = (bf16_t)v;
                }
            }
        }
    }
}

// ---------------- 256x256 8-phase GEMM (m201 structure: T2+T3+T4+T5)
template <int EPI>
__global__ __launch_bounds__(512, 2) void gemm256(
    const bf16_t* __restrict__ A, const bf16_t* __restrict__ Bt,
    const float* __restrict__ bias, bf16_t* __restrict__ outb,
    int M, int N, int K)
{
    __shared__ alignas(1024) bf16_t lds[2][2][256 * 64];
    const int t = threadIdx.x, lane = t & 63, w = t >> 6;
    const int g = lane >> 4, ci = lane & 15;
    const int wr = w >> 2, wc = w & 3;
    const int m0 = blockIdx.y * 256, n0 = blockIdx.x * 256;
    const int NKT = K >> 6;

    f32x4 acc[8][4];
#pragma unroll
    for (int i = 0; i < 8; ++i)
#pragma unroll
        for (int j = 0; j < 4; ++j)
#pragma unroll
            for (int k2 = 0; k2 < 4; ++k2) acc[i][j][k2] = 0.0f;

    const int sw0 = (g ^ (ci & 7)) * 8;
    const int sw1 = ((4 + g) ^ (ci & 7)) * 8;

    auto stage = [&](int h, int ktile, int b) {
#pragma unroll
        for (int i = 0; i < 2; ++i) {
            const int idx = i * 512 + t;
            const int r = idx >> 3;
            const int c = (t & 7) ^ (r & 7);
            const bf16_t* src = ((h < 2) ? A : Bt)
                + (size_t)(((h < 2) ? m0 : n0) + (h & 1) * 128 + r) * K
                + ktile * 64 + c * 8;
            bf16_t* dst = &lds[b][h >> 1][(h & 1) * 8192] + (i * 512 + w * 64) * 8;
            gload_lds16(src, dst);
        }
    };

    bf16x8 a[4][2], b2[2][2][2];

    stage(0, 0, 0); stage(3, 0, 0); stage(1, 0, 0); stage(2, 0, 0);
    if (NKT > 1) { stage(0, 1, 1); stage(3, 1, 1); stage(1, 1, 1); }
    asm volatile("s_waitcnt vmcnt(6)" ::: "memory");
    __builtin_amdgcn_s_barrier();

    for (int kt = 0; kt < NKT; ++kt) {
        const int cur = kt & 1;
        const bf16_t* Ab = &lds[cur][0][0];
        const bf16_t* Bb = &lds[cur][1][0];

#pragma unroll
        for (int mi = 0; mi < 4; ++mi) {
            const bf16_t* ap = Ab + (wr * 64 + mi * 16 + ci) * 64;
            a[mi][0] = *(const bf16x8*)(ap + sw0);
            a[mi][1] = *(const bf16x8*)(ap + sw1);
        }
#pragma unroll
        for (int ni = 0; ni < 2; ++ni) {
            const bf16_t* bp = Bb + (wc * 32 + ni * 16 + ci) * 64;
            b2[0][ni][0] = *(const bf16x8*)(bp + sw0);
            b2[0][ni][1] = *(const bf16x8*)(bp + sw1);
        }
        if (kt + 1 < NKT) stage(2, kt + 1, cur ^ 1);
        __builtin_amdgcn_s_barrier();
        asm volatile("s_waitcnt lgkmcnt(0)" ::: "memory");
        __builtin_amdgcn_sched_barrier(0);
        __builtin_amdgcn_s_setprio(1);
#pragma unroll
        for (int mi = 0; mi < 4; ++mi)
#pragma unroll
            for (int ni = 0; ni < 2; ++ni) {
                acc[mi][ni] = mfma16(a[mi][0], b2[0][ni][0], acc[mi][ni]);
                acc[mi][ni] = mfma16(a[mi][1], b2[0][ni][1], acc[mi][ni]);
            }
        __builtin_amdgcn_s_setprio(0);
        __builtin_amdgcn_s_barrier();

#pragma unroll
        for (int ni = 0; ni < 2; ++ni) {
            const bf16_t* bp = Bb + (128 + wc * 32 + ni * 16 + ci) * 64;
            b2[1][ni][0] = *(const bf16x8*)(bp + sw0);
            b2[1][ni][1] = *(const bf16x8*)(bp + sw1);
        }
        if (kt + 2 < NKT) stage(0, kt + 2, cur);
        __builtin_amdgcn_s_barrier();
        asm volatile("s_waitcnt lgkmcnt(0)" ::: "memory");
        __builtin_amdgcn_sched_barrier(0);
        __builtin_amdgcn_s_setprio(1);
#pragma unroll
        for (int mi = 0; mi < 4; ++mi)
#pragma unroll
            for (int ni = 0; ni < 2; ++ni) {
                acc[mi][2 + ni] = mfma16(a[mi][0], b2[1][ni][0], acc[mi][2 + ni]);
                acc[mi][2 + ni] = mfma16(a[mi][1], b2[1][ni][1], acc[mi][2 + ni]);
            }
        __builtin_amdgcn_s_setprio(0);
        __builtin_amdgcn_s_barrier();

#pragma unroll
        for (int mi = 0; mi < 4; ++mi) {
            const bf16_t* ap = Ab + (128 + wr * 64 + mi * 16 + ci) * 64;
            a[mi][0] = *(const bf16x8*)(ap + sw0);
            a[mi][1] = *(const bf16x8*)(ap + sw1);
        }
        if (kt + 2 < NKT) stage(3, kt + 2, cur);
        __builtin_amdgcn_s_barrier();
        asm volatile("s_waitcnt lgkmcnt(0)" ::: "memory");
        __builtin_amdgcn_sched_barrier(0);
        __builtin_amdgcn_s_setprio(1);
#pragma unroll
        for (int mi = 0; mi < 4; ++mi)
#pragma unroll
            for (int ni = 0; ni < 2; ++ni) {
                acc[4 + mi][2 + ni] = mfma16(a[mi][0], b2[1][ni][0], acc[4 + mi][2 + ni]);
                acc[4 + mi][2 + ni] = mfma16(a[mi][1], b2[1][ni][1], acc[4 + mi][2 + ni]);
            }
        __builtin_amdgcn_s_setprio(0);
        __builtin_amdgcn_s_barrier();

        if (kt + 2 < NKT) stage(1, kt + 2, cur);
        __builtin_amdgcn_s_barrier();
        __builtin_amdgcn_s_setprio(1);
#pragma unroll
        for (int mi = 0; mi < 4; ++mi)
#pragma unroll
            for (int ni = 0; ni < 2; ++ni) {
                acc[4 + mi][ni] = mfma16(a[mi][0], b2[0][ni][0], acc[4 + mi][ni]);
                acc[4 + mi][ni] = mfma16(a[mi][1], b2[0][ni][1], acc[4 + mi][ni]);
            }
        __builtin_amdgcn_s_setprio(0);
        if (kt + 2 < NKT) asm volatile("s_waitcnt vmcnt(6)" ::: "memory");
        else              asm volatile("s_waitcnt vmcnt(0)" ::: "memory");
        __builtin_amdgcn_s_barrier();
    }

#pragma unroll
    for (int mrep = 0; mrep < 8; ++mrep) {
        const int row = m0 + (mrep >> 2) * 128 + wr * 64 + (mrep & 3) * 16 + g * 4;
#pragma unroll
        for (int nrep = 0; nrep < 4; ++nrep) {
            const int col = n0 + (nrep >> 1) * 128 + wc * 32 + (nrep & 1) * 16 + ci;
            const float bv = bias[col];
#pragma unroll
            for (int jr = 0; jr < 4; ++jr) {
                float v = acc[mrep][nrep][jr] + bv;
                if constexpr (EPI == 1) v = gelu_exact(v);
                outb[(size_t)(row + jr) * N + col] = (bf16_t)v;
            }
        }
    }
}

// ---------------- causal flash attention, 32x32 swapped-operand structure
// 4 warps x 32 q-rows = 128 q/block; KVBLK=64 double-buffered.
// S' = mfma(K, Q): C col = lane&31 = q-row -> softmax state is per-lane scalar.
// O' = mfma(V^T, P^T): C col = q-row again -> rescale is per-lane scalar.
// P handoff via per-warp LDS [32][72] (16B-aligned rows, bank-floor spread);
// both PV operands are loaded with the same assumed A/B k-mapping so any
// bijective mis-assumption cancels (only the HW-verified C/D layout is used
// for mask / kpos indexing).
__global__ __launch_bounds__(256, 2) void attn_fwd(
    const bf16_t* __restrict__ qkv, const bf16_t* __restrict__ vt,
    bf16_t* __restrict__ out)
{
    __shared__ alignas(1024) bf16_t Klds[2][64 * 64];
    __shared__ alignas(1024) bf16_t Vlds[2][64 * 64];   // V^T tile [d][kpos]
    __shared__ alignas(1024) bf16_t Plds[4][32 * 72];
    const int t = threadIdx.x, lane = t & 63, w = t >> 6;
    const int hi = lane >> 5, li = lane & 31;
    const int h = blockIdx.x;
    const int y = blockIdx.y;
    const int qb = (y < 16) ? y : (31 - (y - 16));   // balanced pairs per CU
    const int q0 = qb * 128;
    const int qrow = q0 + w * 32 + li;
    const float C1 = 0.125f * 1.4426950408889634f;

    // Q fragments (B-operand): qf[ks] = Q[qrow][ks*16 + hi*8 .. +7]
    bf16x8 qf[4];
#pragma unroll
    for (int ks = 0; ks < 4; ++ks)
        qf[ks] = *(const bf16x8*)(qkv + (size_t)qrow * 3072 + h * 64 + ks * 16 + hi * 8);

    f32x16 oacc[2];
#pragma unroll
    for (int d = 0; d < 2; ++d)
#pragma unroll
        for (int r = 0; r < 16; ++r) oacc[d][r] = 0.0f;
    float m_i = -1e30f, l_i = 0.0f;

    const int NT = q0 / 64 + 2;                       // tiles for the block
    const int wNT = (q0 + w * 32 + 31) / 64 + 1;      // tiles for this warp

    const int sr = t >> 3;                            // staging row 0..31
    const int sx = ((t & 7) ^ (sr & 7)) * 8;          // pre-swizzled src chunk

    auto stageKV = [&](int kt, int b) {
        const size_t kbase = (size_t)(kt * 64) * 3072 + 1024 + h * 64 + sx;
        const size_t vbase = (size_t)h * 262144 + (size_t)kt * 64 + sx;
#pragma unroll
        for (int i = 0; i < 2; ++i) {
            gload_lds16(qkv + kbase + (size_t)(i * 32 + sr) * 3072,
                        (char*)&Klds[b][0] + (size_t)(i * 2048 + t * 8) * 2);
            gload_lds16(vt + vbase + (size_t)(i * 32 + sr) * 4096,
                        (char*)&Vlds[b][0] + (size_t)(i * 2048 + t * 8) * 2);
        }
    };

    stageKV(0, 0);
    for (int kt = 0; kt < NT; ++kt) {
        const int cur = kt & 1;
        asm volatile("s_waitcnt vmcnt(0)" ::: "memory");
        __syncthreads();
        if (kt + 1 < NT) stageKV(kt + 1, cur ^ 1);

        if (kt < wNT) {
            const bf16_t* Kb = &Klds[cur][0];
            const bf16_t* Vb = &Vlds[cur][0];
            f32x16 s0, s1;
#pragma unroll
            for (int r = 0; r < 16; ++r) { s0[r] = 0.0f; s1[r] = 0.0f; }

            __builtin_amdgcn_s_setprio(1);
#pragma unroll
            for (int ks = 0; ks < 4; ++ks) {
                const int cs = ((ks * 2 + hi) ^ (li & 7)) * 8;
                s0 = mfma32(*(const bf16x8*)(Kb + li * 64 + cs), qf[ks], s0);
                s1 = mfma32(*(const bf16x8*)(Kb + (32 + li) * 64 + cs), qf[ks], s1);
            }
            __builtin_amdgcn_s_setprio(0);

            const bool diag = (kt == wNT - 1);
            if (diag) {
                const int kb0 = kt * 64 + 4 * hi;
#pragma unroll
                for (int r = 0; r < 16; ++r) {
                    const int kp0 = kb0 + (r & 3) + 8 * (r >> 2);
                    if (kp0 > qrow) s0[r] = -1e30f;
                    if (kp0 + 32 > qrow) s1[r] = -1e30f;
                }
            }
            float mx = -1e30f;
#pragma unroll
            for (int r = 0; r < 16; ++r) mx = fmaxf(mx, fmaxf(s0[r], s1[r]));
            mx = fmaxf(mx, __shfl_xor(mx, 32));
            const float newm = fmaxf(m_i, mx * C1);
            const float scf = exp2f(m_i - newm);
            m_i = newm;
            float rs0 = 0.0f, rs1 = 0.0f;
#pragma unroll
            for (int r = 0; r < 16; ++r) {
                float p0 = exp2f(fmaf(s0[r], C1, -newm));
                float p1 = exp2f(fmaf(s1[r], C1, -newm));
                s0[r] = p0; s1[r] = p1;
                rs0 += p0; rs1 += p1;
            }
            float rs = rs0 + rs1;
            rs += __shfl_xor(rs, 32);
            l_i = l_i * scf + rs;
#pragma unroll
            for (int r = 0; r < 16; ++r) { oacc[0][r] *= scf; oacc[1][r] *= scf; }

            // P -> per-warp LDS, P[q=li][kpos], kpos = kb2*32 + gi*8 + hi*4 + j
            bf16_t* pw = &Plds[w][0] + li * 72 + hi * 4;
#pragma unroll
            for (int gi = 0; gi < 4; ++gi) {
                bf16x4 a4, b4;
#pragma unroll
                for (int j = 0; j < 4; ++j) {
                    a4[j] = (bf16_t)s0[gi * 4 + j];
                    b4[j] = (bf16_t)s1[gi * 4 + j];
                }
                *(bf16x4*)(pw + gi * 8) = a4;
                *(bf16x4*)(pw + 32 + gi * 8) = b4;
            }
            asm volatile("s_waitcnt lgkmcnt(0)" ::: "memory");
            __builtin_amdgcn_sched_barrier(0);

            const bf16_t* pr = &Plds[w][0] + li * 72 + hi * 8;
            __builtin_amdgcn_s_setprio(1);
#pragma unroll
            for (int ks = 0; ks < 4; ++ks) {
                const bf16x8 pf = *(const bf16x8*)(pr + ks * 16);
                const int cs = ((ks * 2 + hi) ^ (li & 7)) * 8;
                oacc[0] = mfma32(*(const bf16x8*)(Vb + li * 64 + cs), pf, oacc[0]);
                oacc[1] = mfma32(*(const bf16x8*)(Vb + (32 + li) * 64 + cs), pf, oacc[1]);
            }
            __builtin_amdgcn_s_setprio(0);
        }
        __syncthreads();
    }

    const float inv = 1.0f / l_i;
    bf16_t* ob = out + (size_t)qrow * 1024 + h * 64 + hi * 4;
#pragma unroll
    for (int dblk = 0; dblk < 2; ++dblk)
#pragma unroll
        for (int gi = 0; gi < 4; ++gi) {
            bf16x4 o4;
#pragma unroll
            for (int j = 0; j < 4; ++j)
                o4[j] = (bf16_t)(oacc[dblk][gi * 4 + j] * inv);
            *(bf16x4*)(ob + dblk * 32 + gi * 8) = o4;
        }
}

extern "C" void kernel_launch(void* const* d_in, const int* in_sizes, int n_in,
                              void* d_out, int out_size, void* d_ws, size_t ws_size,
                              hipStream_t stream)
{
    const float* x    = (const float*)d_in[0];
    const float* ln1g = (const float*)d_in[1];
    const float* ln1b = (const float*)d_in[2];
    const float* Wqkv = (const float*)d_in[3];
    const float* bqkv = (const float*)d_in[4];
    const float* Wo   = (const float*)d_in[5];
    const float* bo   = (const float*)d_in[6];
    const float* ln2g = (const float*)d_in[7];
    const float* ln2b = (const float*)d_in[8];
    const float* W1   = (const float*)d_in[9];
    const float* b1   = (const float*)d_in[10];
    const float* W2   = (const float*)d_in[11];
    const float* b2   = (const float*)d_in[12];
    float* outp = (float*)d_out;

    char* p = (char*)d_ws;
    bf16_t* WqkvT = (bf16_t*)p; p += (size_t)3072 * 1024 * 2;
    bf16_t* WoT   = (bf16_t*)p; p += (size_t)1024 * 1024 * 2;
    bf16_t* W1T   = (bf16_t*)p; p += (size_t)4096 * 1024 * 2;
    bf16_t* W2T   = (bf16_t*)p; p += (size_t)1024 * 4096 * 2;
    bf16_t* xn    = (bf16_t*)p; p += (size_t)4096 * 1024 * 2;
    bf16_t* qkv   = (bf16_t*)p; p += (size_t)4096 * 3072 * 2;
    bf16_t* vtb   = (bf16_t*)p; p += (size_t)16 * 64 * 4096 * 2;
    bf16_t* attnb = (bf16_t*)p; p += (size_t)4096 * 1024 * 2;
    float*  x2    = (float*)p;  p += (size_t)4096 * 1024 * 4;
    bf16_t* hb    = (bf16_t*)p; p += (size_t)4096 * 1024 * 2;
    bf16_t* g1    = (bf16_t*)p; p += (size_t)4096 * 4096 * 2;

    const dim3 tb(32, 8);
    transpose_w<<<dim3(96, 32),  tb, 0, stream>>>(Wqkv, WqkvT, 1024, 3072);
    transpose_w<<<dim3(32, 32),  tb, 0, stream>>>(Wo,   WoT,   1024, 1024);
    transpose_w<<<dim3(128, 32), tb, 0, stream>>>(W1,   W1T,   1024, 4096);
    transpose_w<<<dim3(32, 128), tb, 0, stream>>>(W2,   W2T,   4096, 1024);

    ln_bf16<<<4096, 256, 0, stream>>>(x, ln1g, ln1b, xn);
    gemm256<0><<<dim3(12, 16), 512, 0, stream>>>(xn, WqkvT, bqkv,
                                                 qkv, 4096, 3072, 1024);
    vtrans<<<dim3(128, 2, 16), tb, 0, stream>>>(qkv, vtb);
    attn_fwd<<<dim3(16, 32), 256, 0, stream>>>(qkv, vtb, attnb);
    gemm_bt<2><<<dim3(8, 32), 256, 0, stream>>>(attnb, WoT, bo, x,
                                                nullptr, x2, 4096, 1024, 1024);
    ln_bf16<<<4096, 256, 0, stream>>>(x2, ln2g, ln2b, hb);
    gemm256<1><<<dim3(16, 16), 512, 0, stream>>>(hb, W1T, b1,
                                                 g1, 4096, 4096, 1024);
    gemm_bt<2><<<dim3(8, 32), 256, 0, stream>>>(g1, W2T, b2, x2,
                                                nullptr, outp, 4096, 1024, 4096);
}

// Round 5
// 349.206 us; speedup vs baseline: 1.5333x; 1.0260x over previous
//
#include <hip/hip_runtime.h>
#include <math.h>

typedef __bf16 bf16_t;
typedef __attribute__((ext_vector_type(8))) __bf16 bf16x8;
typedef __attribute__((ext_vector_type(4))) __bf16 bf16x4;
typedef __attribute__((ext_vector_type(4))) float f32x4;
typedef __attribute__((ext_vector_type(16))) float f32x16;
typedef __attribute__((ext_vector_type(4))) unsigned int u32x4;

#define T_LEN 4096
#define C_DIM 1024
#define NH 16
#define HD 64

__device__ __forceinline__ void gload_lds16(const void* g, void* l) {
    __builtin_amdgcn_global_load_lds(
        (__attribute__((address_space(1))) void*)(g),
        (__attribute__((address_space(3))) void*)(l), 16, 0, 0);
}

__device__ __forceinline__ f32x4 mfma16(bf16x8 a, bf16x8 b, f32x4 c) {
    return __builtin_amdgcn_mfma_f32_16x16x32_bf16(a, b, c, 0, 0, 0);
}

__device__ __forceinline__ f32x16 mfma32(bf16x8 a, bf16x8 b, f32x16 c) {
    return __builtin_amdgcn_mfma_f32_32x32x16_bf16(a, b, c, 0, 0, 0);
}

__device__ __forceinline__ float gelu_exact(float v) {
    return 0.5f * v * (1.0f + erff(v * 0.7071067811865476f));
}

// T12: build two PV B-fragments (k-chunks of 16) from 16 P values held in
// C/D layout (kp = 4*hi + (r&3) + 8*(r>>2) + base). cvt_pk packs pairs;
// permlane32_swap exchanges vdst's upper 32 lanes with vsrc's lower 32 ->
// one swap yields w0 (own/partner) and w2 (partner/own) simultaneously.
__device__ __forceinline__ void make_frags2(const f32x16 s, bf16x8& fx, bf16x8& fy) {
    unsigned a0, a1, b0, b1;
    asm("v_cvt_pk_bf16_f32 %0, %1, %2" : "=v"(a0) : "v"(s[0]), "v"(s[1]));
    asm("v_cvt_pk_bf16_f32 %0, %1, %2" : "=v"(a1) : "v"(s[2]), "v"(s[3]));
    asm("v_cvt_pk_bf16_f32 %0, %1, %2" : "=v"(b0) : "v"(s[4]), "v"(s[5]));
    asm("v_cvt_pk_bf16_f32 %0, %1, %2" : "=v"(b1) : "v"(s[6]), "v"(s[7]));
    asm("v_permlane32_swap_b32 %0, %1" : "+v"(a0), "+v"(b0));
    asm("v_permlane32_swap_b32 %0, %1" : "+v"(a1), "+v"(b1));
    u32x4 wa = {a0, a1, b0, b1};
    fx = __builtin_bit_cast(bf16x8, wa);
    unsigned c0, c1, d0, d1;
    asm("v_cvt_pk_bf16_f32 %0, %1, %2" : "=v"(c0) : "v"(s[8]), "v"(s[9]));
    asm("v_cvt_pk_bf16_f32 %0, %1, %2" : "=v"(c1) : "v"(s[10]), "v"(s[11]));
    asm("v_cvt_pk_bf16_f32 %0, %1, %2" : "=v"(d0) : "v"(s[12]), "v"(s[13]));
    asm("v_cvt_pk_bf16_f32 %0, %1, %2" : "=v"(d1) : "v"(s[14]), "v"(s[15]));
    asm("v_permlane32_swap_b32 %0, %1" : "+v"(c0), "+v"(d0));
    asm("v_permlane32_swap_b32 %0, %1" : "+v"(c1), "+v"(d1));
    u32x4 wb = {c0, c1, d0, d1};
    fy = __builtin_bit_cast(bf16x8, wb);
}

// ---------------- weight transpose+convert: in fp32 [R][C] -> out bf16 [C][R]
__global__ __launch_bounds__(256) void transpose_w(
    const float* __restrict__ in, bf16_t* __restrict__ out, int R, int C)
{
    __shared__ float tile[32][33];
    const int tx = threadIdx.x, ty = threadIdx.y;
    const int c0 = blockIdx.x * 32, r0 = blockIdx.y * 32;
#pragma unroll
    for (int j = 0; j < 4; ++j)
        tile[ty + j * 8][tx] = in[(size_t)(r0 + ty + j * 8) * C + c0 + tx];
    __syncthreads();
#pragma unroll
    for (int j = 0; j < 4; ++j)
        out[(size_t)(c0 + ty + j * 8) * R + r0 + tx] = (bf16_t)tile[tx][ty + j * 8];
}

// ---------------- per-head V transpose: qkv bf16 [T][3C] -> vt [H][64][T]
__global__ __launch_bounds__(256) void vtrans(
    const bf16_t* __restrict__ qkv, bf16_t* __restrict__ vt)
{
    __shared__ bf16_t tile[32][33];
    const int tx = threadIdx.x, ty = threadIdx.y;
    const int h = blockIdx.z;
    const int t0 = blockIdx.x * 32, d0 = blockIdx.y * 32;
#pragma unroll
    for (int j = 0; j < 4; ++j)
        tile[ty + j * 8][tx] =
            qkv[(size_t)(t0 + ty + j * 8) * 3072 + 2048 + h * 64 + d0 + tx];
    __syncthreads();
#pragma unroll
    for (int j = 0; j < 4; ++j)
        vt[(size_t)h * (64 * 4096) + (size_t)(d0 + ty + j * 8) * 4096 + t0 + tx] =
            tile[tx][ty + j * 8];
}

// ---------------- LayerNorm fp32 -> bf16
__global__ __launch_bounds__(256) void ln_bf16(
    const float* __restrict__ x, const float* __restrict__ gam,
    const float* __restrict__ bet, bf16_t* __restrict__ out)
{
    const int row = blockIdx.x, t = threadIdx.x;
    const float4 v = *(const float4*)(x + (size_t)row * 1024 + t * 4);
    float s1 = v.x + v.y + v.z + v.w;
    float s2 = v.x * v.x + v.y * v.y + v.z * v.z + v.w * v.w;
#pragma unroll
    for (int m = 1; m < 64; m <<= 1) {
        s1 += __shfl_xor(s1, m);
        s2 += __shfl_xor(s2, m);
    }
    __shared__ float red[8];
    if ((t & 63) == 0) { red[(t >> 6) * 2] = s1; red[(t >> 6) * 2 + 1] = s2; }
    __syncthreads();
    s1 = red[0] + red[2] + red[4] + red[6];
    s2 = red[1] + red[3] + red[5] + red[7];
    const float mu = s1 * (1.0f / 1024.0f);
    const float inv = rsqrtf(s2 * (1.0f / 1024.0f) - mu * mu + 1e-5f);
    const float4 gg = *(const float4*)(gam + t * 4);
    const float4 bb = *(const float4*)(bet + t * 4);
    bf16x4 o;
    o[0] = (bf16_t)((v.x - mu) * inv * gg.x + bb.x);
    o[1] = (bf16_t)((v.y - mu) * inv * gg.y + bb.y);
    o[2] = (bf16_t)((v.z - mu) * inv * gg.z + bb.z);
    o[3] = (bf16_t)((v.w - mu) * inv * gg.w + bb.w);
    *(bf16x4*)(out + (size_t)row * 1024 + t * 4) = o;
}

// ---------------- 128x128 GEMM (m97 structure), for N=1024 shapes
// EPI: 0 = bf16 out, 1 = gelu -> bf16 out, 2 = +res(fp32) -> fp32 out
template <int EPI>
__global__ __launch_bounds__(256) void gemm_bt(
    const bf16_t* __restrict__ A, const bf16_t* __restrict__ Bt,
    const float* __restrict__ bias, const float* __restrict__ res,
    bf16_t* __restrict__ outb, float* __restrict__ outf,
    int M, int N, int K)
{
    __shared__ alignas(1024) bf16_t Alds[128 * 32];
    __shared__ alignas(1024) bf16_t Blds[128 * 32];
    const int t = threadIdx.x;
    const int lane = t & 63, w = t >> 6;
    const int wr = w >> 1, wc = w & 1;
    const int m0 = blockIdx.y * 128, n0 = blockIdx.x * 128;
    const int g = lane >> 4, ci = lane & 15;

    f32x4 acc[4][4];
#pragma unroll
    for (int i = 0; i < 4; ++i)
#pragma unroll
        for (int j = 0; j < 4; ++j)
#pragma unroll
            for (int k = 0; k < 4; ++k) acc[i][j][k] = 0.0f;

    const int r0 = t >> 2;
    const int cc = (t & 3) * 8;
    char* aB = (char*)Alds + w * 1024;
    char* bB = (char*)Blds + w * 1024;
    const int nkt = K >> 5;
    for (int kt = 0; kt < nkt; ++kt) {
        const int kk = kt * 32;
        gload_lds16(A + (size_t)(m0 + r0) * K + kk + cc, aB);
        gload_lds16(A + (size_t)(m0 + r0 + 64) * K + kk + cc, aB + 4096);
        gload_lds16(Bt + (size_t)(n0 + r0) * K + kk + cc, bB);
        gload_lds16(Bt + (size_t)(n0 + r0 + 64) * K + kk + cc, bB + 4096);
        __syncthreads();
        const bf16_t* ap = Alds + (wr * 64 + ci) * 32 + g * 8;
        const bf16_t* bp = Blds + (wc * 64 + ci) * 32 + g * 8;
        bf16x8 af[4], bf[4];
#pragma unroll
        for (int mt = 0; mt < 4; ++mt) af[mt] = *(const bf16x8*)(ap + mt * 16 * 32);
#pragma unroll
        for (int nt = 0; nt < 4; ++nt) bf[nt] = *(const bf16x8*)(bp + nt * 16 * 32);
#pragma unroll
        for (int mt = 0; mt < 4; ++mt)
#pragma unroll
            for (int nt = 0; nt < 4; ++nt)
                acc[mt][nt] = mfma16(af[mt], bf[nt], acc[mt][nt]);
        __syncthreads();
    }

#pragma unroll
    for (int nt = 0; nt < 4; ++nt) {
        const int col = n0 + wc * 64 + nt * 16 + ci;
        const float bv = bias[col];
#pragma unroll
        for (int mt = 0; mt < 4; ++mt) {
            const int row = m0 + wr * 64 + mt * 16 + g * 4;
#pragma unroll
            for (int r = 0; r < 4; ++r) {
                float v = acc[mt][nt][r] + bv;
                if constexpr (EPI == 1) v = gelu_exact(v);
                if constexpr (EPI == 2) {
                    outf[(size_t)(row + r) * N + col] =
                        v + res[(size_t)(row + r) * N + col];
                } else {
                    outb[(size_t)(row + r) * N + col] = (bf16_t)v;
                }
            }
        }
    }
}

// ---------------- 256x256 8-phase GEMM (m201 structure: T2+T3+T4+T5)
template <int EPI>
__global__ __launch_bounds__(512, 2) void gemm256(
    const bf16_t* __restrict__ A, const bf16_t* __restrict__ Bt,
    const float* __restrict__ bias, bf16_t* __restrict__ outb,
    int M, int N, int K)
{
    __shared__ alignas(1024) bf16_t lds[2][2][256 * 64];
    const int t = threadIdx.x, lane = t & 63, w = t >> 6;
    const int g = lane >> 4, ci = lane & 15;
    const int wr = w >> 2, wc = w & 3;
    const int m0 = blockIdx.y * 256, n0 = blockIdx.x * 256;
    const int NKT = K >> 6;

    f32x4 acc[8][4];
#pragma unroll
    for (int i = 0; i < 8; ++i)
#pragma unroll
        for (int j = 0; j < 4; ++j)
#pragma unroll
            for (int k2 = 0; k2 < 4; ++k2) acc[i][j][k2] = 0.0f;

    const int sw0 = (g ^ (ci & 7)) * 8;
    const int sw1 = ((4 + g) ^ (ci & 7)) * 8;

    auto stage = [&](int h, int ktile, int b) {
#pragma unroll
        for (int i = 0; i < 2; ++i) {
            const int idx = i * 512 + t;
            const int r = idx >> 3;
            const int c = (t & 7) ^ (r & 7);
            const bf16_t* src = ((h < 2) ? A : Bt)
                + (size_t)(((h < 2) ? m0 : n0) + (h & 1) * 128 + r) * K
                + ktile * 64 + c * 8;
            bf16_t* dst = &lds[b][h >> 1][(h & 1) * 8192] + (i * 512 + w * 64) * 8;
            gload_lds16(src, dst);
        }
    };

    bf16x8 a[4][2], b2[2][2][2];

    stage(0, 0, 0); stage(3, 0, 0); stage(1, 0, 0); stage(2, 0, 0);
    if (NKT > 1) { stage(0, 1, 1); stage(3, 1, 1); stage(1, 1, 1); }
    asm volatile("s_waitcnt vmcnt(6)" ::: "memory");
    __builtin_amdgcn_s_barrier();

    for (int kt = 0; kt < NKT; ++kt) {
        const int cur = kt & 1;
        const bf16_t* Ab = &lds[cur][0][0];
        const bf16_t* Bb = &lds[cur][1][0];

#pragma unroll
        for (int mi = 0; mi < 4; ++mi) {
            const bf16_t* ap = Ab + (wr * 64 + mi * 16 + ci) * 64;
            a[mi][0] = *(const bf16x8*)(ap + sw0);
            a[mi][1] = *(const bf16x8*)(ap + sw1);
        }
#pragma unroll
        for (int ni = 0; ni < 2; ++ni) {
            const bf16_t* bp = Bb + (wc * 32 + ni * 16 + ci) * 64;
            b2[0][ni][0] = *(const bf16x8*)(bp + sw0);
            b2[0][ni][1] = *(const bf16x8*)(bp + sw1);
        }
        if (kt + 1 < NKT) stage(2, kt + 1, cur ^ 1);
        __builtin_amdgcn_s_barrier();
        asm volatile("s_waitcnt lgkmcnt(0)" ::: "memory");
        __builtin_amdgcn_sched_barrier(0);
        __builtin_amdgcn_s_setprio(1);
#pragma unroll
        for (int mi = 0; mi < 4; ++mi)
#pragma unroll
            for (int ni = 0; ni < 2; ++ni) {
                acc[mi][ni] = mfma16(a[mi][0], b2[0][ni][0], acc[mi][ni]);
                acc[mi][ni] = mfma16(a[mi][1], b2[0][ni][1], acc[mi][ni]);
            }
        __builtin_amdgcn_s_setprio(0);
        __builtin_amdgcn_s_barrier();

#pragma unroll
        for (int ni = 0; ni < 2; ++ni) {
            const bf16_t* bp = Bb + (128 + wc * 32 + ni * 16 + ci) * 64;
            b2[1][ni][0] = *(const bf16x8*)(bp + sw0);
            b2[1][ni][1] = *(const bf16x8*)(bp + sw1);
        }
        if (kt + 2 < NKT) stage(0, kt + 2, cur);
        __builtin_amdgcn_s_barrier();
        asm volatile("s_waitcnt lgkmcnt(0)" ::: "memory");
        __builtin_amdgcn_sched_barrier(0);
        __builtin_amdgcn_s_setprio(1);
#pragma unroll
        for (int mi = 0; mi < 4; ++mi)
#pragma unroll
            for (int ni = 0; ni < 2; ++ni) {
                acc[mi][2 + ni] = mfma16(a[mi][0], b2[1][ni][0], acc[mi][2 + ni]);
                acc[mi][2 + ni] = mfma16(a[mi][1], b2[1][ni][1], acc[mi][2 + ni]);
            }
        __builtin_amdgcn_s_setprio(0);
        __builtin_amdgcn_s_barrier();

#pragma unroll
        for (int mi = 0; mi < 4; ++mi) {
            const bf16_t* ap = Ab + (128 + wr * 64 + mi * 16 + ci) * 64;
            a[mi][0] = *(const bf16x8*)(ap + sw0);
            a[mi][1] = *(const bf16x8*)(ap + sw1);
        }
        if (kt + 2 < NKT) stage(3, kt + 2, cur);
        __builtin_amdgcn_s_barrier();
        asm volatile("s_waitcnt lgkmcnt(0)" ::: "memory");
        __builtin_amdgcn_sched_barrier(0);
        __builtin_amdgcn_s_setprio(1);
#pragma unroll
        for (int mi = 0; mi < 4; ++mi)
#pragma unroll
            for (int ni = 0; ni < 2; ++ni) {
                acc[4 + mi][2 + ni] = mfma16(a[mi][0], b2[1][ni][0], acc[4 + mi][2 + ni]);
                acc[4 + mi][2 + ni] = mfma16(a[mi][1], b2[1][ni][1], acc[4 + mi][2 + ni]);
            }
        __builtin_amdgcn_s_setprio(0);
        __builtin_amdgcn_s_barrier();

        if (kt + 2 < NKT) stage(1, kt + 2, cur);
        __builtin_amdgcn_s_barrier();
        __builtin_amdgcn_s_setprio(1);
#pragma unroll
        for (int mi = 0; mi < 4; ++mi)
#pragma unroll
            for (int ni = 0; ni < 2; ++ni) {
                acc[4 + mi][ni] = mfma16(a[mi][0], b2[0][ni][0], acc[4 + mi][ni]);
                acc[4 + mi][ni] = mfma16(a[mi][1], b2[0][ni][1], acc[4 + mi][ni]);
            }
        __builtin_amdgcn_s_setprio(0);
        if (kt + 2 < NKT) asm volatile("s_waitcnt vmcnt(6)" ::: "memory");
        else              asm volatile("s_waitcnt vmcnt(0)" ::: "memory");
        __builtin_amdgcn_s_barrier();
    }

#pragma unroll
    for (int mrep = 0; mrep < 8; ++mrep) {
        const int row = m0 + (mrep >> 2) * 128 + wr * 64 + (mrep & 3) * 16 + g * 4;
#pragma unroll
        for (int nrep = 0; nrep < 4; ++nrep) {
            const int col = n0 + (nrep >> 1) * 128 + wc * 32 + (nrep & 1) * 16 + ci;
            const float bv = bias[col];
#pragma unroll
            for (int jr = 0; jr < 4; ++jr) {
                float v = acc[mrep][nrep][jr] + bv;
                if constexpr (EPI == 1) v = gelu_exact(v);
                outb[(size_t)(row + jr) * N + col] = (bf16_t)v;
            }
        }
    }
}

// ---------------- causal flash attention, 32x32 swapped-operand structure
// 4 warps x 32 q-rows = 128 q/block; KVBLK=64 double-buffered.
// Swizzle key is (row>>2)&7: the 8 lanes in each li%4 bank-class have li>>2
// spanning 0..7 (bijection) -> 32 lanes cover 32 banks, 2-way max (free).
// T12: P stays in registers (cvt_pk + permlane32_swap), no Plds.
// T13: defer-max rescale (THR=8).
__global__ __launch_bounds__(256, 2) void attn_fwd(
    const bf16_t* __restrict__ qkv, const bf16_t* __restrict__ vt,
    bf16_t* __restrict__ out)
{
    __shared__ alignas(1024) bf16_t Klds[2][64 * 64];
    __shared__ alignas(1024) bf16_t Vlds[2][64 * 64];   // V^T tile [d][kpos]
    const int t = threadIdx.x, lane = t & 63, w = t >> 6;
    const int hi = lane >> 5, li = lane & 31;
    const int lq = li >> 2;                              // read-swizzle key
    const int h = blockIdx.x;
    const int y = blockIdx.y;
    const int qb = (y < 16) ? y : (47 - y);              // balanced pairs per CU
    const int q0 = qb * 128;
    const int qrow = q0 + w * 32 + li;
    const float C1 = 0.125f * 1.4426950408889634f;

    bf16x8 qf[4];
#pragma unroll
    for (int ks = 0; ks < 4; ++ks)
        qf[ks] = *(const bf16x8*)(qkv + (size_t)qrow * 3072 + h * 64 + ks * 16 + hi * 8);

    f32x16 oacc[2];
#pragma unroll
    for (int d = 0; d < 2; ++d)
#pragma unroll
        for (int r = 0; r < 16; ++r) oacc[d][r] = 0.0f;
    float m_i = -1e30f, l_i = 0.0f;

    const int NT = q0 / 64 + 2;
    const int wNT = (q0 + w * 32 + 31) / 64 + 1;

    const int sr = t >> 3;                               // staging row 0..31
    const int sx = ((t & 7) ^ ((sr >> 2) & 7)) * 8;      // key = (row>>2)&7

    auto stageKV = [&](int kt, int b) {
        const size_t kbase = (size_t)(kt * 64) * 3072 + 1024 + h * 64 + sx;
        const size_t vbase = (size_t)h * 262144 + (size_t)kt * 64 + sx;
#pragma unroll
        for (int i = 0; i < 2; ++i) {
            gload_lds16(qkv + kbase + (size_t)(i * 32 + sr) * 3072,
                        (char*)&Klds[b][0] + (size_t)(i * 2048 + t * 8) * 2);
            gload_lds16(vt + vbase + (size_t)(i * 32 + sr) * 4096,
                        (char*)&Vlds[b][0] + (size_t)(i * 2048 + t * 8) * 2);
        }
    };

    stageKV(0, 0);
    for (int kt = 0; kt < NT; ++kt) {
        const int cur = kt & 1;
        asm volatile("s_waitcnt vmcnt(0)" ::: "memory");
        __syncthreads();
        if (kt + 1 < NT) stageKV(kt + 1, cur ^ 1);

        if (kt < wNT) {
            const bf16_t* Kb = &Klds[cur][0];
            const bf16_t* Vb = &Vlds[cur][0];
            f32x16 s0, s1;
#pragma unroll
            for (int r = 0; r < 16; ++r) { s0[r] = 0.0f; s1[r] = 0.0f; }

            __builtin_amdgcn_s_setprio(1);
#pragma unroll
            for (int ks = 0; ks < 4; ++ks) {
                const int cs = ((ks * 2 + hi) ^ lq) * 8;
                s0 = mfma32(*(const bf16x8*)(Kb + li * 64 + cs), qf[ks], s0);
                s1 = mfma32(*(const bf16x8*)(Kb + (32 + li) * 64 + cs), qf[ks], s1);
            }
            __builtin_amdgcn_s_setprio(0);

            // V fragments issued early: ds_read latency hides under softmax
            bf16x8 vf[4][2];
#pragma unroll
            for (int ks = 0; ks < 4; ++ks) {
                const int cs = ((ks * 2 + hi) ^ lq) * 8;
                vf[ks][0] = *(const bf16x8*)(Vb + li * 64 + cs);
                vf[ks][1] = *(const bf16x8*)(Vb + (32 + li) * 64 + cs);
            }

            const bool diag = (kt == wNT - 1);
            if (diag) {
                const int kb0 = kt * 64 + 4 * hi;
#pragma unroll
                for (int r = 0; r < 16; ++r) {
                    const int kp0 = kb0 + (r & 3) + 8 * (r >> 2);
                    if (kp0 > qrow) s0[r] = -1e30f;
                    if (kp0 + 32 > qrow) s1[r] = -1e30f;
                }
            }
            float mx = -1e30f;
#pragma unroll
            for (int r = 0; r < 16; ++r) mx = fmaxf(mx, fmaxf(s0[r], s1[r]));
            mx = fmaxf(mx, __shfl_xor(mx, 32));
            const float pmax = mx * C1;
            if (!__all(pmax - m_i <= 8.0f)) {            // T13 defer-max
                const float newm = fmaxf(m_i, pmax);
                const float scf = exp2f(m_i - newm);
                m_i = newm;
                l_i *= scf;
#pragma unroll
                for (int r = 0; r < 16; ++r) { oacc[0][r] *= scf; oacc[1][r] *= scf; }
            }
            float rs = 0.0f;
#pragma unroll
            for (int r = 0; r < 16; ++r) {
                float p0 = exp2f(fmaf(s0[r], C1, -m_i));
                float p1 = exp2f(fmaf(s1[r], C1, -m_i));
                s0[r] = p0; s1[r] = p1;
                rs += p0 + p1;
            }
            rs += __shfl_xor(rs, 32);
            l_i += rs;

            bf16x8 pf[4];
            make_frags2(s0, pf[0], pf[1]);
            make_frags2(s1, pf[2], pf[3]);

            __builtin_amdgcn_s_setprio(1);
#pragma unroll
            for (int ks = 0; ks < 4; ++ks) {
                oacc[0] = mfma32(vf[ks][0], pf[ks], oacc[0]);
                oacc[1] = mfma32(vf[ks][1], pf[ks], oacc[1]);
            }
            __builtin_amdgcn_s_setprio(0);
        }
        __syncthreads();
    }

    const float inv = 1.0f / l_i;
    bf16_t* ob = out + (size_t)qrow * 1024 + h * 64 + hi * 4;
#pragma unroll
    for (int dblk = 0; dblk < 2; ++dblk)
#pragma unroll
        for (int gi = 0; gi < 4; ++gi) {
            bf16x4 o4;
#pragma unroll
            for (int j = 0; j < 4; ++j)
                o4[j] = (bf16_t)(oacc[dblk][gi * 4 + j] * inv);
            *(bf16x4*)(ob + dblk * 32 + gi * 8) = o4;
        }
}

extern "C" void kernel_launch(void* const* d_in, const int* in_sizes, int n_in,
                              void* d_out, int out_size, void* d_ws, size_t ws_size,
                              hipStream_t stream)
{
    const float* x    = (const float*)d_in[0];
    const float* ln1g = (const float*)d_in[1];
    const float* ln1b = (const float*)d_in[2];
    const float* Wqkv = (const float*)d_in[3];
    const float* bqkv = (const float*)d_in[4];
    const float* Wo   = (const float*)d_in[5];
    const float* bo   = (const float*)d_in[6];
    const float* ln2g = (const float*)d_in[7];
    const float* ln2b = (const float*)d_in[8];
    const float* W1   = (const float*)d_in[9];
    const float* b1   = (const float*)d_in[10];
    const float* W2   = (const float*)d_in[11];
    const float* b2   = (const float*)d_in[12];
    float* outp = (float*)d_out;

    char* p = (char*)d_ws;
    bf16_t* WqkvT = (bf16_t*)p; p += (size_t)3072 * 1024 * 2;
    bf16_t* WoT   = (bf16_t*)p; p += (size_t)1024 * 1024 * 2;
    bf16_t* W1T   = (bf16_t*)p; p += (size_t)4096 * 1024 * 2;
    bf16_t* W2T   = (bf16_t*)p; p += (size_t)1024 * 4096 * 2;
    bf16_t* xn    = (bf16_t*)p; p += (size_t)4096 * 1024 * 2;
    bf16_t* qkv   = (bf16_t*)p; p += (size_t)4096 * 3072 * 2;
    bf16_t* vtb   = (bf16_t*)p; p += (size_t)16 * 64 * 4096 * 2;
    bf16_t* attnb = (bf16_t*)p; p += (size_t)4096 * 1024 * 2;
    float*  x2    = (float*)p;  p += (size_t)4096 * 1024 * 4;
    bf16_t* hb    = (bf16_t*)p; p += (size_t)4096 * 1024 * 2;
    bf16_t* g1    = (bf16_t*)p; p += (size_t)4096 * 4096 * 2;

    const dim3 tb(32, 8);
    transpose_w<<<dim3(96, 32),  tb, 0, stream>>>(Wqkv, WqkvT, 1024, 3072);
    transpose_w<<<dim3(32, 32),  tb, 0, stream>>>(Wo,   WoT,   1024, 1024);
    transpose_w<<<dim3(128, 32), tb, 0, stream>>>(W1,   W1T,   1024, 4096);
    transpose_w<<<dim3(32, 128), tb, 0, stream>>>(W2,   W2T,   4096, 1024);

    ln_bf16<<<4096, 256, 0, stream>>>(x, ln1g, ln1b, xn);
    gemm256<0><<<dim3(12, 16), 512, 0, stream>>>(xn, WqkvT, bqkv,
                                                 qkv, 4096, 3072, 1024);
    vtrans<<<dim3(128, 2, 16), tb, 0, stream>>>(qkv, vtb);
    attn_fwd<<<dim3(16, 32), 256, 0, stream>>>(qkv, vtb, attnb);
    gemm_bt<2><<<dim3(8, 32), 256, 0, stream>>>(attnb, WoT, bo, x,
                                                nullptr, x2, 4096, 1024, 1024);
    ln_bf16<<<4096, 256, 0, stream>>>(x2, ln2g, ln2b, hb);
    gemm256<1><<<dim3(16, 16), 512, 0, stream>>>(hb, W1T, b1,
                                                 g1, 4096, 4096, 1024);
    gemm_bt<2><<<dim3(8, 32), 256, 0, stream>>>(g1, W2T, b2, x2,
                                                nullptr, outp, 4096, 1024, 4096);
}